// Round 1
// baseline (863.613 us; speedup 1.0000x reference)
//
#include <hip/hip_runtime.h>
#include <stdint.h>

// ---------------------------------------------------------------------------
// ResidueGraphModel: aanet_proj (512->1024->1024->512->80, ReLU) -> in_net
// (80->512) -> GIN sum-aggregation + MLP (512->512->512) -> out_net (512->80).
// bf16 MFMA GEMMs (fp32 accumulate), 128x128 tiles, BK=64, 16x16x32 MFMA.
// R9: double-buffered K-pipeline with counted vmcnt (T3+T4). Old loop drained
// the whole global_load_lds queue at every __syncthreads (vmcnt(0) before
// s_barrier = the ~30% MfmaUtil stall). New loop: raw s_barrier + explicit
// "s_waitcnt vmcnt(8)" waits only the PREVIOUS K-tile's 8 loads; the next
// K-tile's 8 loads stay in flight across the barrier. LDS 32->64 KB (2 bufs),
// 2 blocks/CU (== achieved occupancy before). setprio(1) around MFMA cluster.
// GEMM core otherwise frozen (R2/R4): XOR-swizzled LDS (0 bank conflicts),
// operand-swapped MFMA (packed 8B C stores), XCD-grouped decode, row-padded
// A buffers (no clamp), aggregation before in_net (80-dim gather), edge
// scatter riding inside L1's dispatch.
// Outputs fp32: d_out = [peptide_mask (N*80) | peptide_feat (N*80)].
// ---------------------------------------------------------------------------

using bf16x8 = __attribute__((ext_vector_type(8))) short;
using f32x4  = __attribute__((ext_vector_type(4))) float;

__device__ inline unsigned short f2bf(float f) {
    union { float f; unsigned u; } v; v.f = f;
    unsigned u = v.u;
    u += 0x7FFFu + ((u >> 16) & 1u);   // RNE
    return (unsigned short)(u >> 16);
}
__device__ inline float bf2f(unsigned u16) {
    return __uint_as_float(u16 << 16);
}

// ------------- merged preprocessing ----------------------------------------
// Block ranges: [0, tEnd) -> weight transpose+convert (32x32 tiles, 256 thr)
//               [tEnd, cEnd) -> feat f32->bf16 convert (1024 elems/block)
//               [cEnd, eEnd) -> edge dst counting (256 edges/block)
struct PreDescs {
    const float* W[8]; unsigned short* Wt[8];
    int K[8], M[8], Kp[8], ntx[8], start[8];
    int tEnd, cEnd, eEnd;
    const float* feat; unsigned short* featb; int nFeat;
    const int* ei; int E; int* cnt;
};

__global__ __launch_bounds__(256) void rg_preprocess(PreDescs d) {
    int b = blockIdx.x;
    int tid = threadIdx.x;
    if (b < d.tEnd) {
        // transpose: W[K][M] f32 -> Wt[Mp][Kp] bf16 (pad with 0)
        __shared__ float t[32][33];
        int di = 0;
#pragma unroll
        for (int i = 1; i < 8; ++i) if (b >= d.start[i]) di = i;
        int local = b - d.start[di];
        int bx = local % d.ntx[di];
        int by = local / d.ntx[di];
        const float* W = d.W[di];
        unsigned short* Wt = d.Wt[di];
        int K = d.K[di], M = d.M[di], Kp = d.Kp[di];
        int mb = bx * 32, kb = by * 32;
        int tx = tid & 31, tg = tid >> 5;   // 8 rows per pass, 4 passes
#pragma unroll
        for (int p = 0; p < 4; ++p) {
            int r = tg + p * 8;             // tile row (k-dir)
            int k = kb + r, m = mb + tx;
            t[r][tx] = (k < K && m < M) ? W[(size_t)k * M + m] : 0.f;
        }
        __syncthreads();
#pragma unroll
        for (int p = 0; p < 4; ++p) {
            int r = tg + p * 8;             // tile row (m-dir)
            int mo = mb + r, ko = kb + tx;
            Wt[(size_t)mo * Kp + ko] = f2bf(t[tx][r]);
        }
    } else if (b < d.cEnd) {
        int i = ((b - d.tEnd) * 256 + tid) * 4;
        if (i + 3 < d.nFeat) {
            float4 v = *(const float4*)(d.feat + i);
            ushort4 o; o.x = f2bf(v.x); o.y = f2bf(v.y); o.z = f2bf(v.z); o.w = f2bf(v.w);
            *(ushort4*)(d.featb + i) = o;
        }
    } else {
        int e = (b - d.cEnd) * 256 + tid;
        if (e < d.E) atomicAdd(&d.cnt[d.ei[d.E + e]], 1);
    }
}

// ---------------- GEMM body: C[N,Mp] = act(A[N,Kp] @ Wt[Mp,Kp]^T + b) -------
// XOR swizzle: LDS chunk q (16B) of a tile row r holds global chunk
// (q&7)^(r&7); staging lane loads the matching global address, fragment
// reads apply the same XOR -> zero measured bank conflicts.
// Operand swap: weights as first MFMA operand -> acc regs hold 4 consecutive
// output columns -> 8B packed stores (32B/row per store instruction).
// R9 pipeline: dbuf LDS; per K-tile: compute buf[kt&1] | s_barrier |
// stage(kt+2 into freed buf) + s_waitcnt vmcnt(8) (only kt+1's loads) |
// s_barrier. vmcnt(0) only at the tail. Loads span barriers -> no drain stall.
template <bool RELU, bool OUT_BF, bool OUT_F32, bool DEGB, int MT>
__device__ __forceinline__ void gemm_body(
    int bid,
    const unsigned short* __restrict__ A, const unsigned short* __restrict__ Bt,
    const float* __restrict__ bias, const int* __restrict__ deg, int Mvalid,
    unsigned short* __restrict__ outB, float* __restrict__ outF,
    int Nrows, int Kp, int Mp, int gN)
{
    __shared__ __align__(16) unsigned short As[2][128 * 64];
    __shared__ __align__(16) unsigned short Bs[2][128 * 64];

    // XCD-grouped decode: a row strip's MT col-blocks share (bid&7), 8 apart
    // in issue order -> A strip stays hot in L2/L3 across column passes.
    int xcd = bid & 7;
    int slot = bid >> 3;
    int c = slot % MT;
    int rsub = slot / MT;
    int rt = rsub * 8 + xcd;
    if (rt >= gN) return;
    const int rowBase = rt * 128;
    const int nBase   = c * 128;

    const int tid  = threadIdx.x;
    const int lane = tid & 63;
    const int w    = tid >> 6;
    const int wm   = w & 1, wn = w >> 1;

    f32x4 acc[4][4];
#pragma unroll
    for (int i = 0; i < 4; ++i)
#pragma unroll
        for (int j = 0; j < 4; ++j) acc[i][j] = (f32x4){0.f, 0.f, 0.f, 0.f};

    const int nkt = Kp >> 6;   // >= 2 for every layer (min K=128)

    // stage one K-tile (8 global_load_lds per thread: 4 A + 4 B)
    auto stage = [&](int buf, int kt) {
        const int k0 = kt << 6;
#pragma unroll
        for (int i = 0; i < 4; ++i) {
            int q   = i * 256 + tid;       // LDS 16B-chunk slot
            int r   = q >> 3;
            int cbg = (q & 7) ^ (r & 7);   // global chunk staged into slot q
            const unsigned short* gp = A + (size_t)(rowBase + r) * Kp + k0 + cbg * 8;
            __builtin_amdgcn_global_load_lds(
                (const __attribute__((address_space(1))) void*)gp,
                (__attribute__((address_space(3))) void*)(&As[buf][q * 8]), 16, 0, 0);
        }
#pragma unroll
        for (int i = 0; i < 4; ++i) {
            int q   = i * 256 + tid;
            int r   = q >> 3;
            int cbg = (q & 7) ^ (r & 7);
            const unsigned short* gp = Bt + (size_t)(nBase + r) * Kp + k0 + cbg * 8;
            __builtin_amdgcn_global_load_lds(
                (const __attribute__((address_space(1))) void*)gp,
                (__attribute__((address_space(3))) void*)(&Bs[buf][q * 8]), 16, 0, 0);
        }
    };

    // prologue: two K-tiles in flight; wait only the first (vmcnt(8) leaves
    // kt1's 8 loads outstanding across the barrier).
    stage(0, 0);
    stage(1, 1);
    asm volatile("s_waitcnt vmcnt(8)" ::: "memory");
    __builtin_amdgcn_sched_barrier(0);
    __builtin_amdgcn_s_barrier();
    __builtin_amdgcn_sched_barrier(0);

    for (int kt = 0; kt < nkt; ++kt) {
        const int cur = kt & 1;
#pragma unroll
        for (int kk = 0; kk < 2; ++kk) {
            bf16x8 a[4], b[4];
            const int cb = kk * 4 + (lane >> 4);
#pragma unroll
            for (int i = 0; i < 4; ++i) {
                int r = wm * 64 + i * 16 + (lane & 15);
                a[i] = *(const bf16x8*)&As[cur][(r * 8 + (cb ^ (r & 7))) * 8];
            }
#pragma unroll
            for (int j = 0; j < 4; ++j) {
                int r = wn * 64 + j * 16 + (lane & 15);
                b[j] = *(const bf16x8*)&Bs[cur][(r * 8 + (cb ^ (r & 7))) * 8];
            }
            __builtin_amdgcn_s_setprio(1);
#pragma unroll
            for (int i = 0; i < 4; ++i)
#pragma unroll
                for (int j = 0; j < 4; ++j)
                    // swapped: weights first -> D cols from regs, rows from lane
                    acc[i][j] = __builtin_amdgcn_mfma_f32_16x16x32_bf16(b[j], a[i], acc[i][j], 0, 0, 0);
            __builtin_amdgcn_s_setprio(0);
        }
        if (kt + 1 == nkt) break;          // uniform: no trailing barriers
        __builtin_amdgcn_sched_barrier(0);
        __builtin_amdgcn_s_barrier();      // all waves done reading buf[cur]
        if (kt + 2 < nkt) {
            stage(cur, kt + 2);            // refill freed buffer
            asm volatile("s_waitcnt vmcnt(8)" ::: "memory");  // kt+1 ready; kt+2 in flight
        } else {
            asm volatile("s_waitcnt vmcnt(0)" ::: "memory");  // tail drain (last tile)
        }
        __builtin_amdgcn_sched_barrier(0);
        __builtin_amdgcn_s_barrier();      // publish buf[cur^1]
        __builtin_amdgcn_sched_barrier(0);
    }

    // epilogue (swapped layout): row = ...+(lane&15); col = ...+quad*4+reg
    const int quad = lane >> 4;
#pragma unroll
    for (int i = 0; i < 4; ++i) {
        int row = rowBase + wm * 64 + i * 16 + (lane & 15);
        if (row >= Nrows) continue;
        float sc = 1.f;
        if (DEGB) sc = 1.f + (float)deg[row];
#pragma unroll
        for (int j = 0; j < 4; ++j) {
            int colb = nBase + wn * 64 + j * 16 + quad * 4;
            float4 bv = (colb < Mvalid) ? *(const float4*)(bias + colb)
                                        : (float4){0.f, 0.f, 0.f, 0.f};
            float v0 = acc[i][j][0] + sc * bv.x;
            float v1 = acc[i][j][1] + sc * bv.y;
            float v2 = acc[i][j][2] + sc * bv.z;
            float v3 = acc[i][j][3] + sc * bv.w;
            if (RELU) {
                v0 = v0 > 0.f ? v0 : 0.f; v1 = v1 > 0.f ? v1 : 0.f;
                v2 = v2 > 0.f ? v2 : 0.f; v3 = v3 > 0.f ? v3 : 0.f;
            }
            if (OUT_BF) {
                ushort4 o; o.x = f2bf(v0); o.y = f2bf(v1); o.z = f2bf(v2); o.w = f2bf(v3);
                *(ushort4*)(outB + (size_t)row * Mp + colb) = o;
            }
            if (OUT_F32) {
                if (colb < Mvalid)
                    *(float4*)(outF + (size_t)row * Mvalid + colb) = (float4){v0, v1, v2, v3};
            }
        }
    }
}

template <bool RELU, bool OUT_BF, bool OUT_F32, bool DEGB, int MT>
__global__ __launch_bounds__(256) void rg_gemm(
    const unsigned short* __restrict__ A, const unsigned short* __restrict__ Bt,
    const float* __restrict__ bias, const int* __restrict__ deg, int Mvalid,
    unsigned short* __restrict__ outB, float* __restrict__ outF,
    int Nrows, int Kp, int Mp, int gN)
{
    gemm_body<RELU, OUT_BF, OUT_F32, DEGB, MT>(blockIdx.x, A, Bt, bias, deg,
                                               Mvalid, outB, outF, Nrows, Kp, Mp, gN);
}

// L1 GEMM + edge scatter in one dispatch: blocks [0, gemmBlocks) do the GEMM,
// the rest scatter edges into CSR (independent work, disjoint memory; scatter
// backfills CUs as GEMM blocks retire -> hidden behind compute).
__global__ __launch_bounds__(256) void rg_gemm_l1_scatter(
    const unsigned short* __restrict__ A, const unsigned short* __restrict__ Bt,
    const float* __restrict__ bias, int Mvalid,
    unsigned short* __restrict__ outB, int Nrows, int Kp, int Mp, int gN,
    int gemmBlocks, const int* __restrict__ ei, int E,
    int* __restrict__ cursor, int* __restrict__ cols)
{
    int bid = blockIdx.x;
    if (bid < gemmBlocks) {
        gemm_body<true, true, false, false, 8>(bid, A, Bt, bias, nullptr,
                                               Mvalid, outB, nullptr, Nrows, Kp, Mp, gN);
    } else {
        int e = (bid - gemmBlocks) * 256 + threadIdx.x;
        if (e < E) {
            int d = ei[E + e];
            int p = atomicAdd(&cursor[d], 1);
            cols[p] = ei[e];
        }
    }
}

// ---------------- merged scan (3 dispatches -> 1) ---------------------------
// 49 blocks x 1024 threads, co-resident (grid << 256 CUs). Stages were
// already 49-block / 1-wave shaped -> merge loses no parallelism.
__device__ __forceinline__ void rg_gridbar(int* bar, int nb, int phase) {
    __syncthreads();
    if (threadIdx.x == 0) {
        __threadfence();
        atomicAdd(bar, 1);
        int target = phase * nb;
        while (__hip_atomic_load(bar, __ATOMIC_RELAXED, __HIP_MEMORY_SCOPE_AGENT) < target) {}
        __threadfence();
    }
    __syncthreads();
}

__global__ __launch_bounds__(1024) void rg_scan_all(
    const int* __restrict__ cnt, int* __restrict__ rowptr, int* __restrict__ cursor,
    int* __restrict__ bsums, int* bar, int Nn, int E, int nb)
{
    __shared__ int sd[1024];
    const int tid = threadIdx.x;
    const int bid = blockIdx.x;
    const int i   = bid * 1024 + tid;

    // stage 1: block-local inclusive scan of this block's 1024-chunk
    int v = (i < Nn) ? cnt[i] : 0;
    sd[tid] = v;
    __syncthreads();
    for (int off = 1; off < 1024; off <<= 1) {
        int t = (tid >= off) ? sd[tid - off] : 0;
        __syncthreads();
        sd[tid] += t;
        __syncthreads();
    }
    if (tid == 1023) bsums[bid] = sd[1023];
    rg_gridbar(bar, nb, 1);

    // stage 2: exclusive wave-scan of block sums (block 0, nb <= 64)
    if (bid == 0 && tid < 64) {
        int bv = (tid < nb) ? bsums[tid] : 0;
        int incl = bv;
#pragma unroll
        for (int off = 1; off < 64; off <<= 1) {
            int t = __shfl_up(incl, off, 64);
            if (tid >= off) incl += t;
        }
        if (tid < nb) bsums[tid] = incl - bv;   // exclusive
    }
    rg_gridbar(bar, nb, 2);

    // stage 3: write rowptr + cursor (sd persisted across barriers)
    if (i < Nn) {
        int ex = sd[tid] - v + bsums[bid];
        rowptr[i] = ex; cursor[i] = ex;
    }
    if (i == 0) rowptr[Nn] = E;
}

// ---------------- 80-dim aggregation: s[i] = pf[i] + sum_{src->i} pf[src] --
// pf is [Npad,128] bf16. One wave per node, 1 uint (2 cols) per lane.
// Edge loop unrolled x8: 8 independent outstanding gathers per iteration.
__global__ __launch_bounds__(256) void rg_agg80(
    const unsigned short* __restrict__ pf, const int* __restrict__ rowptr,
    const int* __restrict__ cols, unsigned short* __restrict__ s, int Nn)
{
    int node = blockIdx.x * 4 + (threadIdx.x >> 6);
    if (node >= Nn) return;
    int lane = threadIdx.x & 63;
    const unsigned* xp = (const unsigned*)pf;   // 64 uints per row
    size_t off = (size_t)node * 64 + lane;
    unsigned u = xp[off];
    float a0 = bf2f(u & 0xffffu), a1 = bf2f(u >> 16);
    int beg = rowptr[node], end = rowptr[node + 1];
    int e = beg;
    for (; e + 8 <= end; e += 8) {
        unsigned v[8];
#pragma unroll
        for (int t = 0; t < 8; ++t) v[t] = xp[(size_t)cols[e + t] * 64 + lane];
#pragma unroll
        for (int t = 0; t < 8; ++t) { a0 += bf2f(v[t] & 0xffffu); a1 += bf2f(v[t] >> 16); }
    }
    for (; e < end; ++e) {
        unsigned v = xp[(size_t)cols[e] * 64 + lane];
        a0 += bf2f(v & 0xffffu); a1 += bf2f(v >> 16);
    }
    unsigned o = (unsigned)f2bf(a0) | ((unsigned)f2bf(a1) << 16);
    ((unsigned*)s)[off] = o;
}

// ---------------------------------------------------------------------------
extern "C" void kernel_launch(void* const* d_in, const int* in_sizes, int n_in,
                              void* d_out, int out_size, void* d_ws, size_t ws_size,
                              hipStream_t stream)
{
    const float* feat = (const float*)d_in[0];
    const int*   ei   = (const int*)d_in[1];
    const float* W1 = (const float*)d_in[2];  const float* b1 = (const float*)d_in[3];
    const float* W2 = (const float*)d_in[4];  const float* b2 = (const float*)d_in[5];
    const float* W3 = (const float*)d_in[6];  const float* b3 = (const float*)d_in[7];
    const float* W4 = (const float*)d_in[8];  const float* b4 = (const float*)d_in[9];
    const float* Wi = (const float*)d_in[10]; const float* bi = (const float*)d_in[11];
    const float* Wg1 = (const float*)d_in[12]; const float* bg1 = (const float*)d_in[13];
    const float* Wg2 = (const float*)d_in[14]; const float* bg2 = (const float*)d_in[15];
    const float* Wo = (const float*)d_in[16]; const float* bo = (const float*)d_in[17];

    const int N = in_sizes[0] / 512;   // 50000
    const int E = in_sizes[1] / 2;     // 800000
    const int gN = (N + 127) / 128;    // 391
    const int Npad = gN * 128;         // 50048: GEMM A-loads never clamp

    char* ws = (char*)d_ws;
    size_t o = 0;
    auto alloc = [&](size_t bytes) { char* p = ws + o; o += (bytes + 255) & ~(size_t)255; return p; };
    unsigned short* bufA = (unsigned short*)alloc((size_t)Npad * 1024 * 2); // h1 / pf / g
    unsigned short* bufB = (unsigned short*)alloc((size_t)Npad * 1024 * 2); // h2 / r1
    unsigned short* bufC = (unsigned short*)alloc((size_t)Npad * 512 * 2);  // A0 / h3 / s / g2
    unsigned short* W1t = (unsigned short*)alloc((size_t)1024 * 512 * 2);
    unsigned short* W2t = (unsigned short*)alloc((size_t)1024 * 1024 * 2);
    unsigned short* W3t = (unsigned short*)alloc((size_t)512 * 1024 * 2);
    unsigned short* W4t = (unsigned short*)alloc((size_t)128 * 512 * 2);
    unsigned short* Wit = (unsigned short*)alloc((size_t)512 * 128 * 2);
    unsigned short* Wg1t = (unsigned short*)alloc((size_t)512 * 512 * 2);
    unsigned short* Wg2t = (unsigned short*)alloc((size_t)512 * 512 * 2);
    unsigned short* Wot = (unsigned short*)alloc((size_t)128 * 512 * 2);
    int* cnt    = (int*)alloc((size_t)(N + 64) * 4);  // +bar tail (one memset)
    int* bar    = cnt + N;
    int* rowptr = (int*)alloc((size_t)(N + 1) * 4);
    int* cursor = (int*)alloc((size_t)N * 4);
    int* cols   = (int*)alloc((size_t)E * 4);
    int* bsums  = (int*)alloc(256);

    float* out_mask = (float*)d_out;                  // [N,80]
    float* out_feat = (float*)d_out + (size_t)N * 80; // [N,80]

    // ---- merged preprocessing: transposes + feat convert + edge count ----
    hipMemsetAsync(cnt, 0, (size_t)(N + 64) * 4, stream);   // zeroes cnt AND bar
    {
        PreDescs d;
        const float* Ws[8]  = {W1, W2, W3, W4, Wi, Wg1, Wg2, Wo};
        unsigned short* Ts[8] = {W1t, W2t, W3t, W4t, Wit, Wg1t, Wg2t, Wot};
        int Ks[8]  = {512, 1024, 1024, 512, 80, 512, 512, 512};
        int Ms[8]  = {1024, 1024, 512, 80, 512, 512, 512, 80};
        int Kps[8] = {512, 1024, 1024, 512, 128, 512, 512, 512};
        int Mps[8] = {1024, 1024, 512, 128, 512, 512, 512, 128};
        int st = 0;
        for (int i = 0; i < 8; ++i) {
            d.W[i] = Ws[i]; d.Wt[i] = Ts[i];
            d.K[i] = Ks[i]; d.M[i] = Ms[i]; d.Kp[i] = Kps[i];
            d.ntx[i] = Mps[i] / 32;
            d.start[i] = st;
            st += (Mps[i] / 32) * (Kps[i] / 32);
        }
        d.tEnd = st;
        d.cEnd = st + (N * 512) / 1024;
        d.eEnd = d.cEnd + (E + 255) / 256;
        d.feat = feat; d.featb = bufC; d.nFeat = N * 512;
        d.ei = ei; d.E = E; d.cnt = cnt;
        rg_preprocess<<<d.eEnd, 256, 0, stream>>>(d);
    }

    // ---- CSR scan: one cooperative kernel (49 blocks) ----
    const int nb = (N + 1023) / 1024;   // 49 <= 64 (wave-scan limit)
    rg_scan_all<<<nb, 1024, 0, stream>>>(cnt, rowptr, cursor, bsums, bar, N, E, nb);

    const int rg8 = ((gN + 7) / 8) * 8;      // 392
    auto grid = [&](int MT) { return dim3(rg8 * MT); };

    // L1: h1 = relu(A0 @ W1 + b1)   [N,1024]  + edge scatter riding along
    {
        const int gemmBlocks = rg8 * 8;             // 3136
        const int scatBlocks = (E + 255) / 256;     // 3125
        rg_gemm_l1_scatter<<<dim3(gemmBlocks + scatBlocks), 256, 0, stream>>>(
            bufC, W1t, b1, 1024, bufA, N, 512, 1024, gN,
            gemmBlocks, ei, E, cursor, cols);
    }

    // L2: h2 = relu(h1 @ W2 + b2)   [N,1024]
    rg_gemm<true, true, false, false, 8><<<grid(8), 256, 0, stream>>>(bufA, W2t, b2, nullptr, 1024, bufB, nullptr, N, 1024, 1024, gN);
    // L3: h3 = relu(h2 @ W3 + b3)   [N,512]
    rg_gemm<true, true, false, false, 4><<<grid(4), 256, 0, stream>>>(bufB, W3t, b3, nullptr, 512, bufC, nullptr, N, 1024, 512, gN);
    // L4: pf = h3 @ W4 + b4  -> fp32 out_feat + bf16 padded [N,128]
    rg_gemm<false, true, true, false, 1><<<grid(1), 256, 0, stream>>>(bufC, W4t, b4, nullptr, 80, bufA, out_feat, N, 512, 128, gN);

    // 80-dim aggregation: s = pf + segsum(pf[src]) -> bufC[:, :128]
    rg_agg80<<<(N + 3) / 4, 256, 0, stream>>>(bufA, rowptr, cols, bufC, N);

    // L5: g = s @ Win + (1+deg)*bin  [N,512]   (agg moved before affine in_net)
    rg_gemm<false, true, false, true, 4><<<grid(4), 256, 0, stream>>>(bufC, Wit, bi, cnt, 512, bufA, nullptr, N, 128, 512, gN);
    // L6: r1 = relu(g @ Wg1 + bg1)  [N,512]
    rg_gemm<true, true, false, false, 4><<<grid(4), 256, 0, stream>>>(bufA, Wg1t, bg1, nullptr, 512, bufB, nullptr, N, 512, 512, gN);
    // L7: g2 = r1 @ Wg2 + bg2       [N,512]
    rg_gemm<false, true, false, false, 4><<<grid(4), 256, 0, stream>>>(bufB, Wg2t, bg2, nullptr, 512, bufC, nullptr, N, 512, 512, gN);
    // L8: mask = g2 @ Wout + bout -> fp32 out_mask
    rg_gemm<false, false, true, false, 1><<<grid(1), 256, 0, stream>>>(bufC, Wot, bo, nullptr, 80, nullptr, out_mask, N, 512, 128, gN);
}

// Round 2
// 847.520 us; speedup vs baseline: 1.0190x; 1.0190x over previous
//
#include <hip/hip_runtime.h>
#include <stdint.h>

// ---------------------------------------------------------------------------
// ResidueGraphModel: aanet_proj (512->1024->1024->512->80, ReLU) -> in_net
// (80->512) -> GIN sum-aggregation + MLP (512->512->512) -> out_net (512->80).
// R10: revert R9's dbuf-128x128 (occupancy loss, T4-null on 2-phase structure).
// Big layers (L1,L2,L3,L6,L7) move to the 256x256 8-phase template (m201):
// 512 thr (2x4 waves), BK=64, 128 KiB LDS (2 dbuf x 2 half per operand),
// per phase {12 ds_read_b128 | stage 1 half-tile global_load_lds | barrier |
// lgkmcnt(0) | setprio+16 MFMA | barrier}; counted vmcnt(4) once per K-tile,
// vmcnt(0) only at tail. Half-stagger chosen so each LDS write targets a
// region last READ in a strictly earlier phase (race-free under lockstep).
// Small-M layers (L4,L5,L8) keep the proven R8 128x128 single-buffer body.
// GEMM core invariants: XOR-swizzled LDS (0 bank conflicts), operand-swapped
// MFMA (packed 8B C stores), XCD-grouped decode, clamped A-row staging,
// aggregation before in_net (80-dim gather), edge scatter riding in L1.
// Outputs fp32: d_out = [peptide_mask (N*80) | peptide_feat (N*80)].
// ---------------------------------------------------------------------------

using bf16x8 = __attribute__((ext_vector_type(8))) short;
using f32x4  = __attribute__((ext_vector_type(4))) float;

__device__ inline unsigned short f2bf(float f) {
    union { float f; unsigned u; } v; v.f = f;
    unsigned u = v.u;
    u += 0x7FFFu + ((u >> 16) & 1u);   // RNE
    return (unsigned short)(u >> 16);
}
__device__ inline float bf2f(unsigned u16) {
    return __uint_as_float(u16 << 16);
}

// ------------- merged preprocessing ----------------------------------------
struct PreDescs {
    const float* W[8]; unsigned short* Wt[8];
    int K[8], M[8], Kp[8], ntx[8], start[8];
    int tEnd, cEnd, eEnd;
    const float* feat; unsigned short* featb; int nFeat;
    const int* ei; int E; int* cnt;
};

__global__ __launch_bounds__(256) void rg_preprocess(PreDescs d) {
    int b = blockIdx.x;
    int tid = threadIdx.x;
    if (b < d.tEnd) {
        __shared__ float t[32][33];
        int di = 0;
#pragma unroll
        for (int i = 1; i < 8; ++i) if (b >= d.start[i]) di = i;
        int local = b - d.start[di];
        int bx = local % d.ntx[di];
        int by = local / d.ntx[di];
        const float* W = d.W[di];
        unsigned short* Wt = d.Wt[di];
        int K = d.K[di], M = d.M[di], Kp = d.Kp[di];
        int mb = bx * 32, kb = by * 32;
        int tx = tid & 31, tg = tid >> 5;
#pragma unroll
        for (int p = 0; p < 4; ++p) {
            int r = tg + p * 8;
            int k = kb + r, m = mb + tx;
            t[r][tx] = (k < K && m < M) ? W[(size_t)k * M + m] : 0.f;
        }
        __syncthreads();
#pragma unroll
        for (int p = 0; p < 4; ++p) {
            int r = tg + p * 8;
            int mo = mb + r, ko = kb + tx;
            Wt[(size_t)mo * Kp + ko] = f2bf(t[tx][r]);
        }
    } else if (b < d.cEnd) {
        int i = ((b - d.tEnd) * 256 + tid) * 4;
        if (i + 3 < d.nFeat) {
            float4 v = *(const float4*)(d.feat + i);
            ushort4 o; o.x = f2bf(v.x); o.y = f2bf(v.y); o.z = f2bf(v.z); o.w = f2bf(v.w);
            *(ushort4*)(d.featb + i) = o;
        }
    } else {
        int e = (b - d.cEnd) * 256 + tid;
        if (e < d.E) atomicAdd(&d.cnt[d.ei[d.E + e]], 1);
    }
}

// ---------------- 128x128 GEMM body (R8, single-buffer) ---------------------
template <bool RELU, bool OUT_BF, bool OUT_F32, bool DEGB, int MT>
__device__ __forceinline__ void gemm_body(
    int bid,
    const unsigned short* __restrict__ A, const unsigned short* __restrict__ Bt,
    const float* __restrict__ bias, const int* __restrict__ deg, int Mvalid,
    unsigned short* __restrict__ outB, float* __restrict__ outF,
    int Nrows, int Kp, int Mp, int gN)
{
    __shared__ __align__(16) unsigned short As[128 * 64];
    __shared__ __align__(16) unsigned short Bs[128 * 64];

    int xcd = bid & 7;
    int slot = bid >> 3;
    int c = slot % MT;
    int rsub = slot / MT;
    int rt = rsub * 8 + xcd;
    if (rt >= gN) return;
    const int rowBase = rt * 128;
    const int nBase   = c * 128;

    const int tid  = threadIdx.x;
    const int lane = tid & 63;
    const int w    = tid >> 6;
    const int wm   = w & 1, wn = w >> 1;

    f32x4 acc[4][4];
#pragma unroll
    for (int i = 0; i < 4; ++i)
#pragma unroll
        for (int j = 0; j < 4; ++j) acc[i][j] = (f32x4){0.f, 0.f, 0.f, 0.f};

    const int nkt = Kp >> 6;
    for (int kt = 0; kt < nkt; ++kt) {
        __syncthreads();
        const int k0 = kt * 64;
#pragma unroll
        for (int i = 0; i < 4; ++i) {
            int q   = i * 256 + tid;
            int r   = q >> 3;
            int cbg = (q & 7) ^ (r & 7);
            const unsigned short* gp = A + (size_t)(rowBase + r) * Kp + k0 + cbg * 8;
            __builtin_amdgcn_global_load_lds(
                (const __attribute__((address_space(1))) void*)gp,
                (__attribute__((address_space(3))) void*)(&As[q * 8]), 16, 0, 0);
        }
#pragma unroll
        for (int i = 0; i < 4; ++i) {
            int q   = i * 256 + tid;
            int r   = q >> 3;
            int cbg = (q & 7) ^ (r & 7);
            const unsigned short* gp = Bt + (size_t)(nBase + r) * Kp + k0 + cbg * 8;
            __builtin_amdgcn_global_load_lds(
                (const __attribute__((address_space(1))) void*)gp,
                (__attribute__((address_space(3))) void*)(&Bs[q * 8]), 16, 0, 0);
        }
        __syncthreads();
#pragma unroll
        for (int kk = 0; kk < 2; ++kk) {
            bf16x8 a[4], b[4];
            const int cb = kk * 4 + (lane >> 4);
#pragma unroll
            for (int i = 0; i < 4; ++i) {
                int r = wm * 64 + i * 16 + (lane & 15);
                a[i] = *(const bf16x8*)&As[(r * 8 + (cb ^ (r & 7))) * 8];
            }
#pragma unroll
            for (int j = 0; j < 4; ++j) {
                int r = wn * 64 + j * 16 + (lane & 15);
                b[j] = *(const bf16x8*)&Bs[(r * 8 + (cb ^ (r & 7))) * 8];
            }
#pragma unroll
            for (int i = 0; i < 4; ++i)
#pragma unroll
                for (int j = 0; j < 4; ++j)
                    acc[i][j] = __builtin_amdgcn_mfma_f32_16x16x32_bf16(b[j], a[i], acc[i][j], 0, 0, 0);
        }
    }

    const int quad = lane >> 4;
#pragma unroll
    for (int i = 0; i < 4; ++i) {
        int row = rowBase + wm * 64 + i * 16 + (lane & 15);
        if (row >= Nrows) continue;
        float sc = 1.f;
        if (DEGB) sc = 1.f + (float)deg[row];
#pragma unroll
        for (int j = 0; j < 4; ++j) {
            int colb = nBase + wn * 64 + j * 16 + quad * 4;
            float4 bv = (colb < Mvalid) ? *(const float4*)(bias + colb)
                                        : (float4){0.f, 0.f, 0.f, 0.f};
            float v0 = acc[i][j][0] + sc * bv.x;
            float v1 = acc[i][j][1] + sc * bv.y;
            float v2 = acc[i][j][2] + sc * bv.z;
            float v3 = acc[i][j][3] + sc * bv.w;
            if (RELU) {
                v0 = v0 > 0.f ? v0 : 0.f; v1 = v1 > 0.f ? v1 : 0.f;
                v2 = v2 > 0.f ? v2 : 0.f; v3 = v3 > 0.f ? v3 : 0.f;
            }
            if (OUT_BF) {
                ushort4 o; o.x = f2bf(v0); o.y = f2bf(v1); o.z = f2bf(v2); o.w = f2bf(v3);
                *(ushort4*)(outB + (size_t)row * Mp + colb) = o;
            }
            if (OUT_F32) {
                if (colb < Mvalid)
                    *(float4*)(outF + (size_t)row * Mvalid + colb) = (float4){v0, v1, v2, v3};
            }
        }
    }
}

template <bool RELU, bool OUT_BF, bool OUT_F32, bool DEGB, int MT>
__global__ __launch_bounds__(256) void rg_gemm(
    const unsigned short* __restrict__ A, const unsigned short* __restrict__ Bt,
    const float* __restrict__ bias, const int* __restrict__ deg, int Mvalid,
    unsigned short* __restrict__ outB, float* __restrict__ outF,
    int Nrows, int Kp, int Mp, int gN)
{
    gemm_body<RELU, OUT_BF, OUT_F32, DEGB, MT>(blockIdx.x, A, Bt, bias, deg,
                                               Mvalid, outB, outF, Nrows, Kp, Mp, gN);
}

// ---------------- 256x256 8-phase GEMM body (m201 port) ---------------------
// Waves: 8 = 2(wm) x 4(wn); per wave 128x64 output, acc[8][4] f32x4.
// A-half mh holds tile rows where quadrant mh reads: wave wm's quadrant-mh
// rows = (mh*2+wm)*64..+63 -> half0 = tile rows 0..127, half1 = 128..255.
// B-half nh = tile cols [nh*128, +128).  Phase q of K-tile a:
//   q=0:(mh0,nh0) stage Ah1(a+1) | q=1:(mh0,nh1) stage Bh1(a+1)
//   q=2:(mh1,nh0) stage Ah0(a+2) | q=3:(mh1,nh1) stage Bh0(a+2) + vmcnt(4)
// Writes always target regions whose last read was an earlier phase.
template <bool RELU, int MT>
__device__ __forceinline__ void gemm256_body(
    int bid,
    const unsigned short* __restrict__ A, const unsigned short* __restrict__ Bt,
    const float* __restrict__ bias, unsigned short* __restrict__ outB,
    int Nrows, int NrowsPad, int Kp, int Mp, int gN2)
{
    __shared__ __align__(16) unsigned short As[2][2][128 * 64];  // [slot][half]
    __shared__ __align__(16) unsigned short Bs[2][2][128 * 64];

    int xcd = bid & 7;
    int slotb = bid >> 3;
    int c = slotb % MT;
    int rsub = slotb / MT;
    int rt = rsub * 8 + xcd;
    if (rt >= gN2) return;
    const int rowBase = rt * 256;
    const int nBase   = c * 256;

    const int tid  = threadIdx.x;
    const int lane = tid & 63;
    const int w    = tid >> 6;      // 0..7
    const int wm   = w & 1;         // 2 row-waves
    const int wn   = w >> 1;        // 4 col-waves

    f32x4 acc[8][4];
#pragma unroll
    for (int i = 0; i < 8; ++i)
#pragma unroll
        for (int j = 0; j < 4; ++j) acc[i][j] = (f32x4){0.f, 0.f, 0.f, 0.f};

    const int nkt = Kp >> 6;        // 8 or 16 here

    // stage one 128x64 half-tile (2 x global_load_lds / thread, 16 KB total)
    auto stageA = [&](int t, int hf) {
        const int k0 = t << 6;
        unsigned short* dst = &As[t & 1][hf][0];
#pragma unroll
        for (int ld = 0; ld < 2; ++ld) {
            int q   = ld * 512 + tid;        // chunk 0..1023
            int r   = q >> 3;                // local row 0..127
            int cbg = (q & 7) ^ (r & 7);
            int grow = rowBase + hf * 128 + r;
            grow = grow < NrowsPad ? grow : NrowsPad - 1;   // last-tile clamp
            const unsigned short* gp = A + (size_t)grow * Kp + k0 + cbg * 8;
            __builtin_amdgcn_global_load_lds(
                (const __attribute__((address_space(1))) void*)gp,
                (__attribute__((address_space(3))) void*)(dst + q * 8), 16, 0, 0);
        }
    };
    auto stageB = [&](int t, int hf) {
        const int k0 = t << 6;
        unsigned short* dst = &Bs[t & 1][hf][0];
#pragma unroll
        for (int ld = 0; ld < 2; ++ld) {
            int q   = ld * 512 + tid;
            int r   = q >> 3;
            int cbg = (q & 7) ^ (r & 7);
            const unsigned short* gp = Bt + (size_t)(nBase + hf * 128 + r) * Kp + k0 + cbg * 8;
            __builtin_amdgcn_global_load_lds(
                (const __attribute__((address_space(1))) void*)gp,
                (__attribute__((address_space(3))) void*)(dst + q * 8), 16, 0, 0);
        }
    };

    // phase: ds-read quadrant frags | stage | (q==3: counted vmcnt) |
    //        barrier | lgkmcnt(0) | setprio+16 MFMA | barrier
    auto phase = [&](int a, int q, int mh, int nh) {
        const int slot = a & 1;
        bf16x8 av[4][2], bv[2][2];
#pragma unroll
        for (int i = 0; i < 4; ++i) {
            int lr = wm * 64 + i * 16 + (lane & 15);
#pragma unroll
            for (int kk = 0; kk < 2; ++kk) {
                int cb = kk * 4 + (lane >> 4);
                av[i][kk] = *(const bf16x8*)&As[slot][mh][(lr * 8 + (cb ^ (lr & 7))) * 8];
            }
        }
#pragma unroll
        for (int j = 0; j < 2; ++j) {
            int lr = wn * 32 + j * 16 + (lane & 15);
#pragma unroll
            for (int kk = 0; kk < 2; ++kk) {
                int cb = kk * 4 + (lane >> 4);
                bv[j][kk] = *(const bf16x8*)&Bs[slot][nh][(lr * 8 + (cb ^ (lr & 7))) * 8];
            }
        }
        if (q == 0) { if (a + 1 < nkt) stageA(a + 1, 1); }
        if (q == 1) { if (a + 1 < nkt) stageB(a + 1, 1); }
        if (q == 2) { if (a + 2 < nkt) stageA(a + 2, 0); }
        if (q == 3) {
            if (a + 2 < nkt) {
                stageB(a + 2, 0);
                asm volatile("s_waitcnt vmcnt(4)" ::: "memory");   // tile a+1 landed
            } else if (a + 1 < nkt) {
                asm volatile("s_waitcnt vmcnt(0)" ::: "memory");   // tail drain
            }
        }
        __builtin_amdgcn_sched_barrier(0);
        __builtin_amdgcn_s_barrier();
        asm volatile("s_waitcnt lgkmcnt(0)" ::: "memory");
        __builtin_amdgcn_sched_barrier(0);
        __builtin_amdgcn_s_setprio(1);
#pragma unroll
        for (int i = 0; i < 4; ++i)
#pragma unroll
            for (int j = 0; j < 2; ++j)
#pragma unroll
                for (int kk = 0; kk < 2; ++kk)
                    acc[mh * 4 + i][nh * 2 + j] = __builtin_amdgcn_mfma_f32_16x16x32_bf16(
                        bv[j][kk], av[i][kk], acc[mh * 4 + i][nh * 2 + j], 0, 0, 0);
        __builtin_amdgcn_s_setprio(0);
        __builtin_amdgcn_sched_barrier(0);
        __builtin_amdgcn_s_barrier();
    };

    // prologue: 6 half-tiles (t0 complete + Ah0,Bh0 of t1); vmcnt(4) -> t0 ready
    stageA(0, 0); stageB(0, 0); stageA(0, 1); stageB(0, 1);
    stageA(1, 0); stageB(1, 0);
    asm volatile("s_waitcnt vmcnt(4)" ::: "memory");
    __builtin_amdgcn_sched_barrier(0);
    __builtin_amdgcn_s_barrier();
    __builtin_amdgcn_sched_barrier(0);

    for (int a = 0; a < nkt; ++a) {
        phase(a, 0, 0, 0);
        phase(a, 1, 0, 1);
        phase(a, 2, 1, 0);
        phase(a, 3, 1, 1);
    }

    // epilogue (swapped layout): row from lane, 4 consecutive cols from regs
    const int quad = lane >> 4;
#pragma unroll
    for (int mi = 0; mi < 8; ++mi) {
        int row = rowBase + ((mi >> 2) * 2 + wm) * 64 + (mi & 3) * 16 + (lane & 15);
        if (row >= Nrows) continue;
#pragma unroll
        for (int nj = 0; nj < 4; ++nj) {
            int colb = nBase + (nj >> 1) * 128 + wn * 32 + (nj & 1) * 16 + quad * 4;
            float4 bvv = *(const float4*)(bias + colb);
            float v0 = acc[mi][nj][0] + bvv.x;
            float v1 = acc[mi][nj][1] + bvv.y;
            float v2 = acc[mi][nj][2] + bvv.z;
            float v3 = acc[mi][nj][3] + bvv.w;
            if (RELU) {
                v0 = v0 > 0.f ? v0 : 0.f; v1 = v1 > 0.f ? v1 : 0.f;
                v2 = v2 > 0.f ? v2 : 0.f; v3 = v3 > 0.f ? v3 : 0.f;
            }
            ushort4 o; o.x = f2bf(v0); o.y = f2bf(v1); o.z = f2bf(v2); o.w = f2bf(v3);
            *(ushort4*)(outB + (size_t)row * Mp + colb) = o;
        }
    }
}

template <bool RELU, int MT>
__global__ __launch_bounds__(512) void rg_gemm256(
    const unsigned short* __restrict__ A, const unsigned short* __restrict__ Bt,
    const float* __restrict__ bias, unsigned short* __restrict__ outB,
    int Nrows, int NrowsPad, int Kp, int Mp, int gN2)
{
    gemm256_body<RELU, MT>(blockIdx.x, A, Bt, bias, outB, Nrows, NrowsPad, Kp, Mp, gN2);
}

// L1 GEMM (256x256) + edge scatter in one dispatch.
__global__ __launch_bounds__(512) void rg_gemm256_l1_scatter(
    const unsigned short* __restrict__ A, const unsigned short* __restrict__ Bt,
    const float* __restrict__ bias, unsigned short* __restrict__ outB,
    int Nrows, int NrowsPad, int Kp, int Mp, int gN2,
    int gemmBlocks, const int* __restrict__ ei, int E,
    int* __restrict__ cursor, int* __restrict__ cols)
{
    int bid = blockIdx.x;
    if (bid < gemmBlocks) {
        gemm256_body<true, 4>(bid, A, Bt, bias, outB, Nrows, NrowsPad, Kp, Mp, gN2);
    } else {
        int e = (bid - gemmBlocks) * 512 + threadIdx.x;
        if (e < E) {
            int d = ei[E + e];
            int p = atomicAdd(&cursor[d], 1);
            cols[p] = ei[e];
        }
    }
}

// ---------------- merged scan (3 dispatches -> 1) ---------------------------
__device__ __forceinline__ void rg_gridbar(int* bar, int nb, int phase) {
    __syncthreads();
    if (threadIdx.x == 0) {
        __threadfence();
        atomicAdd(bar, 1);
        int target = phase * nb;
        while (__hip_atomic_load(bar, __ATOMIC_RELAXED, __HIP_MEMORY_SCOPE_AGENT) < target) {}
        __threadfence();
    }
    __syncthreads();
}

__global__ __launch_bounds__(1024) void rg_scan_all(
    const int* __restrict__ cnt, int* __restrict__ rowptr, int* __restrict__ cursor,
    int* __restrict__ bsums, int* bar, int Nn, int E, int nb)
{
    __shared__ int sd[1024];
    const int tid = threadIdx.x;
    const int bid = blockIdx.x;
    const int i   = bid * 1024 + tid;

    int v = (i < Nn) ? cnt[i] : 0;
    sd[tid] = v;
    __syncthreads();
    for (int off = 1; off < 1024; off <<= 1) {
        int t = (tid >= off) ? sd[tid - off] : 0;
        __syncthreads();
        sd[tid] += t;
        __syncthreads();
    }
    if (tid == 1023) bsums[bid] = sd[1023];
    rg_gridbar(bar, nb, 1);

    if (bid == 0 && tid < 64) {
        int bv = (tid < nb) ? bsums[tid] : 0;
        int incl = bv;
#pragma unroll
        for (int off = 1; off < 64; off <<= 1) {
            int t = __shfl_up(incl, off, 64);
            if (tid >= off) incl += t;
        }
        if (tid < nb) bsums[tid] = incl - bv;
    }
    rg_gridbar(bar, nb, 2);

    if (i < Nn) {
        int ex = sd[tid] - v + bsums[bid];
        rowptr[i] = ex; cursor[i] = ex;
    }
    if (i == 0) rowptr[Nn] = E;
}

// ---------------- 80-dim aggregation ---------------------------------------
__global__ __launch_bounds__(256) void rg_agg80(
    const unsigned short* __restrict__ pf, const int* __restrict__ rowptr,
    const int* __restrict__ cols, unsigned short* __restrict__ s, int Nn)
{
    int node = blockIdx.x * 4 + (threadIdx.x >> 6);
    if (node >= Nn) return;
    int lane = threadIdx.x & 63;
    const unsigned* xp = (const unsigned*)pf;
    size_t off = (size_t)node * 64 + lane;
    unsigned u = xp[off];
    float a0 = bf2f(u & 0xffffu), a1 = bf2f(u >> 16);
    int beg = rowptr[node], end = rowptr[node + 1];
    int e = beg;
    for (; e + 8 <= end; e += 8) {
        unsigned v[8];
#pragma unroll
        for (int t = 0; t < 8; ++t) v[t] = xp[(size_t)cols[e + t] * 64 + lane];
#pragma unroll
        for (int t = 0; t < 8; ++t) { a0 += bf2f(v[t] & 0xffffu); a1 += bf2f(v[t] >> 16); }
    }
    for (; e < end; ++e) {
        unsigned v = xp[(size_t)cols[e] * 64 + lane];
        a0 += bf2f(v & 0xffffu); a1 += bf2f(v >> 16);
    }
    unsigned o = (unsigned)f2bf(a0) | ((unsigned)f2bf(a1) << 16);
    ((unsigned*)s)[off] = o;
}

// ---------------------------------------------------------------------------
extern "C" void kernel_launch(void* const* d_in, const int* in_sizes, int n_in,
                              void* d_out, int out_size, void* d_ws, size_t ws_size,
                              hipStream_t stream)
{
    const float* feat = (const float*)d_in[0];
    const int*   ei   = (const int*)d_in[1];
    const float* W1 = (const float*)d_in[2];  const float* b1 = (const float*)d_in[3];
    const float* W2 = (const float*)d_in[4];  const float* b2 = (const float*)d_in[5];
    const float* W3 = (const float*)d_in[6];  const float* b3 = (const float*)d_in[7];
    const float* W4 = (const float*)d_in[8];  const float* b4 = (const float*)d_in[9];
    const float* Wi = (const float*)d_in[10]; const float* bi = (const float*)d_in[11];
    const float* Wg1 = (const float*)d_in[12]; const float* bg1 = (const float*)d_in[13];
    const float* Wg2 = (const float*)d_in[14]; const float* bg2 = (const float*)d_in[15];
    const float* Wo = (const float*)d_in[16]; const float* bo = (const float*)d_in[17];

    const int N = in_sizes[0] / 512;   // 50000
    const int E = in_sizes[1] / 2;     // 800000
    const int gN = (N + 127) / 128;    // 391
    const int Npad = gN * 128;         // 50048

    char* ws = (char*)d_ws;
    size_t o = 0;
    auto alloc = [&](size_t bytes) { char* p = ws + o; o += (bytes + 255) & ~(size_t)255; return p; };
    unsigned short* bufA = (unsigned short*)alloc((size_t)Npad * 1024 * 2); // h1 / pf / g
    unsigned short* bufB = (unsigned short*)alloc((size_t)Npad * 1024 * 2); // h2 / r1
    unsigned short* bufC = (unsigned short*)alloc((size_t)Npad * 512 * 2);  // A0 / h3 / s / g2
    unsigned short* W1t = (unsigned short*)alloc((size_t)1024 * 512 * 2);
    unsigned short* W2t = (unsigned short*)alloc((size_t)1024 * 1024 * 2);
    unsigned short* W3t = (unsigned short*)alloc((size_t)512 * 1024 * 2);
    unsigned short* W4t = (unsigned short*)alloc((size_t)128 * 512 * 2);
    unsigned short* Wit = (unsigned short*)alloc((size_t)512 * 128 * 2);
    unsigned short* Wg1t = (unsigned short*)alloc((size_t)512 * 512 * 2);
    unsigned short* Wg2t = (unsigned short*)alloc((size_t)512 * 512 * 2);
    unsigned short* Wot = (unsigned short*)alloc((size_t)128 * 512 * 2);
    int* cnt    = (int*)alloc((size_t)(N + 64) * 4);
    int* bar    = cnt + N;
    int* rowptr = (int*)alloc((size_t)(N + 1) * 4);
    int* cursor = (int*)alloc((size_t)N * 4);
    int* cols   = (int*)alloc((size_t)E * 4);
    int* bsums  = (int*)alloc(256);

    float* out_mask = (float*)d_out;                  // [N,80]
    float* out_feat = (float*)d_out + (size_t)N * 80; // [N,80]

    // ---- merged preprocessing ----
    hipMemsetAsync(cnt, 0, (size_t)(N + 64) * 4, stream);
    {
        PreDescs d;
        const float* Ws[8]  = {W1, W2, W3, W4, Wi, Wg1, Wg2, Wo};
        unsigned short* Ts[8] = {W1t, W2t, W3t, W4t, Wit, Wg1t, Wg2t, Wot};
        int Ks[8]  = {512, 1024, 1024, 512, 80, 512, 512, 512};
        int Ms[8]  = {1024, 1024, 512, 80, 512, 512, 512, 80};
        int Kps[8] = {512, 1024, 1024, 512, 128, 512, 512, 512};
        int Mps[8] = {1024, 1024, 512, 128, 512, 512, 512, 128};
        int st = 0;
        for (int i = 0; i < 8; ++i) {
            d.W[i] = Ws[i]; d.Wt[i] = Ts[i];
            d.K[i] = Ks[i]; d.M[i] = Ms[i]; d.Kp[i] = Kps[i];
            d.ntx[i] = Mps[i] / 32;
            d.start[i] = st;
            st += (Mps[i] / 32) * (Kps[i] / 32);
        }
        d.tEnd = st;
        d.cEnd = st + (N * 512) / 1024;
        d.eEnd = d.cEnd + (E + 255) / 256;
        d.feat = feat; d.featb = bufC; d.nFeat = N * 512;
        d.ei = ei; d.E = E; d.cnt = cnt;
        rg_preprocess<<<d.eEnd, 256, 0, stream>>>(d);
    }

    // ---- CSR scan ----
    const int nb = (N + 1023) / 1024;   // 49
    rg_scan_all<<<nb, 1024, 0, stream>>>(cnt, rowptr, cursor, bsums, bar, N, E, nb);

    const int rg8 = ((gN + 7) / 8) * 8;         // 392 (128-tile grid unit)
    auto grid = [&](int MT) { return dim3(rg8 * MT); };
    const int gN2 = (N + 255) / 256;            // 196 (256-tile rows)
    const int rg256 = ((gN2 + 7) / 8) * 8;      // 200

    // L1: h1 = relu(A0 @ W1 + b1)   [N,1024]  (256^2 8-phase) + edge scatter
    {
        const int gemmBlocks = rg256 * 4;            // 800
        const int scatBlocks = (E + 511) / 512;      // 1563
        rg_gemm256_l1_scatter<<<dim3(gemmBlocks + scatBlocks), 512, 0, stream>>>(
            bufC, W1t, b1, bufA, N, Npad, 512, 1024, gN2,
            gemmBlocks, ei, E, cursor, cols);
    }

    // L2: h2 = relu(h1 @ W2 + b2)   [N,1024]   (256^2 8-phase)
    rg_gemm256<true, 4><<<dim3(rg256 * 4), 512, 0, stream>>>(bufA, W2t, b2, bufB, N, Npad, 1024, 1024, gN2);
    // L3: h3 = relu(h2 @ W3 + b3)   [N,512]    (256^2 8-phase)
    rg_gemm256<true, 2><<<dim3(rg256 * 2), 512, 0, stream>>>(bufB, W3t, b3, bufC, N, Npad, 1024, 512, gN2);
    // L4: pf = h3 @ W4 + b4  -> fp32 out_feat + bf16 padded [N,128]  (128^2)
    rg_gemm<false, true, true, false, 1><<<grid(1), 256, 0, stream>>>(bufC, W4t, b4, nullptr, 80, bufA, out_feat, N, 512, 128, gN);

    // 80-dim aggregation: s = pf + segsum(pf[src]) -> bufC[:, :128]
    rg_agg80<<<(N + 3) / 4, 256, 0, stream>>>(bufA, rowptr, cols, bufC, N);

    // L5: g = s @ Win + (1+deg)*bin  [N,512]   (128^2, K=128)
    rg_gemm<false, true, false, true, 4><<<grid(4), 256, 0, stream>>>(bufC, Wit, bi, cnt, 512, bufA, nullptr, N, 128, 512, gN);
    // L6: r1 = relu(g @ Wg1 + bg1)  [N,512]    (256^2 8-phase)
    rg_gemm256<true, 2><<<dim3(rg256 * 2), 512, 0, stream>>>(bufA, Wg1t, bg1, bufB, N, Npad, 512, 512, gN2);
    // L7: g2 = r1 @ Wg2 + bg2       [N,512]    (256^2 8-phase)
    rg_gemm256<false, 2><<<dim3(rg256 * 2), 512, 0, stream>>>(bufB, Wg2t, bg2, bufC, N, Npad, 512, 512, gN2);
    // L8: mask = g2 @ Wout + bout -> fp32 out_mask   (128^2)
    rg_gemm<false, false, true, false, 1><<<grid(1), 256, 0, stream>>>(bufC, Wot, bo, nullptr, 80, nullptr, out_mask, N, 512, 128, gN);
}

// Round 4
// 786.498 us; speedup vs baseline: 1.0980x; 1.0776x over previous
//
#include <hip/hip_runtime.h>
#include <stdint.h>

// ---------------------------------------------------------------------------
// ResidueGraphModel: aanet_proj (512->1024->1024->512->80, ReLU) -> in_net
// (80->512) -> GIN sum-aggregation + MLP (512->512->512) -> out_net (512->80).
// R12 = R11 resubmitted verbatim (R3 bench was an infra container failure;
// audit found no hang/OOB/barrier-divergence path -- see round notes).
// R11: fix R10's fragment double-read. 256x256 template runs 2 phases per
// K-tile: phase0 (rows 0..127) reads A-h0 frags + BOTH B halves into regs;
// phase1 (rows 128..255) reads only A-h1, reuses B from regs. 24 ds_read_b128
// per K-tile per wave (was 48) -> LDS pipe drops below MFMA -> MFMA is the
// critical path. Counted vmcnt(4) once per K-tile (12 outstanding - 8 oldest
// = tile a+1 complete); vmcnt(0) only at tail. 4 barriers/K-tile (was 8).
// __launch_bounds__(512,2) pins VGPR<=256 (acc128+frags64+misc) for 2 w/SIMD.
// Small-M layers (L4,L5,L8) keep the proven R8 128x128 single-buffer body.
// Invariants: XOR-swizzled LDS (0 bank conflicts), operand-swapped MFMA
// (packed 8B C stores), XCD-grouped decode, aggregation before in_net,
// edge scatter riding in L1's dispatch.
// Outputs fp32: d_out = [peptide_mask (N*80) | peptide_feat (N*80)].
// ---------------------------------------------------------------------------

using bf16x8 = __attribute__((ext_vector_type(8))) short;
using f32x4  = __attribute__((ext_vector_type(4))) float;

__device__ inline unsigned short f2bf(float f) {
    union { float f; unsigned u; } v; v.f = f;
    unsigned u = v.u;
    u += 0x7FFFu + ((u >> 16) & 1u);   // RNE
    return (unsigned short)(u >> 16);
}
__device__ inline float bf2f(unsigned u16) {
    return __uint_as_float(u16 << 16);
}

// ------------- merged preprocessing ----------------------------------------
struct PreDescs {
    const float* W[8]; unsigned short* Wt[8];
    int K[8], M[8], Kp[8], ntx[8], start[8];
    int tEnd, cEnd, eEnd;
    const float* feat; unsigned short* featb; int nFeat;
    const int* ei; int E; int* cnt;
};

__global__ __launch_bounds__(256) void rg_preprocess(PreDescs d) {
    int b = blockIdx.x;
    int tid = threadIdx.x;
    if (b < d.tEnd) {
        __shared__ float t[32][33];
        int di = 0;
#pragma unroll
        for (int i = 1; i < 8; ++i) if (b >= d.start[i]) di = i;
        int local = b - d.start[di];
        int bx = local % d.ntx[di];
        int by = local / d.ntx[di];
        const float* W = d.W[di];
        unsigned short* Wt = d.Wt[di];
        int K = d.K[di], M = d.M[di], Kp = d.Kp[di];
        int mb = bx * 32, kb = by * 32;
        int tx = tid & 31, tg = tid >> 5;
#pragma unroll
        for (int p = 0; p < 4; ++p) {
            int r = tg + p * 8;
            int k = kb + r, m = mb + tx;
            t[r][tx] = (k < K && m < M) ? W[(size_t)k * M + m] : 0.f;
        }
        __syncthreads();
#pragma unroll
        for (int p = 0; p < 4; ++p) {
            int r = tg + p * 8;
            int mo = mb + r, ko = kb + tx;
            Wt[(size_t)mo * Kp + ko] = f2bf(t[tx][r]);
        }
    } else if (b < d.cEnd) {
        int i = ((b - d.tEnd) * 256 + tid) * 4;
        if (i + 3 < d.nFeat) {
            float4 v = *(const float4*)(d.feat + i);
            ushort4 o; o.x = f2bf(v.x); o.y = f2bf(v.y); o.z = f2bf(v.z); o.w = f2bf(v.w);
            *(ushort4*)(d.featb + i) = o;
        }
    } else {
        int e = (b - d.cEnd) * 256 + tid;
        if (e < d.E) atomicAdd(&d.cnt[d.ei[d.E + e]], 1);
    }
}

// ---------------- 128x128 GEMM body (R8, single-buffer) ---------------------
template <bool RELU, bool OUT_BF, bool OUT_F32, bool DEGB, int MT>
__device__ __forceinline__ void gemm_body(
    int bid,
    const unsigned short* __restrict__ A, const unsigned short* __restrict__ Bt,
    const float* __restrict__ bias, const int* __restrict__ deg, int Mvalid,
    unsigned short* __restrict__ outB, float* __restrict__ outF,
    int Nrows, int Kp, int Mp, int gN)
{
    __shared__ __align__(16) unsigned short As[128 * 64];
    __shared__ __align__(16) unsigned short Bs[128 * 64];

    int xcd = bid & 7;
    int slot = bid >> 3;
    int c = slot % MT;
    int rsub = slot / MT;
    int rt = rsub * 8 + xcd;
    if (rt >= gN) return;
    const int rowBase = rt * 128;
    const int nBase   = c * 128;

    const int tid  = threadIdx.x;
    const int lane = tid & 63;
    const int w    = tid >> 6;
    const int wm   = w & 1, wn = w >> 1;

    f32x4 acc[4][4];
#pragma unroll
    for (int i = 0; i < 4; ++i)
#pragma unroll
        for (int j = 0; j < 4; ++j) acc[i][j] = (f32x4){0.f, 0.f, 0.f, 0.f};

    const int nkt = Kp >> 6;
    for (int kt = 0; kt < nkt; ++kt) {
        __syncthreads();
        const int k0 = kt * 64;
#pragma unroll
        for (int i = 0; i < 4; ++i) {
            int q   = i * 256 + tid;
            int r   = q >> 3;
            int cbg = (q & 7) ^ (r & 7);
            const unsigned short* gp = A + (size_t)(rowBase + r) * Kp + k0 + cbg * 8;
            __builtin_amdgcn_global_load_lds(
                (const __attribute__((address_space(1))) void*)gp,
                (__attribute__((address_space(3))) void*)(&As[q * 8]), 16, 0, 0);
        }
#pragma unroll
        for (int i = 0; i < 4; ++i) {
            int q   = i * 256 + tid;
            int r   = q >> 3;
            int cbg = (q & 7) ^ (r & 7);
            const unsigned short* gp = Bt + (size_t)(nBase + r) * Kp + k0 + cbg * 8;
            __builtin_amdgcn_global_load_lds(
                (const __attribute__((address_space(1))) void*)gp,
                (__attribute__((address_space(3))) void*)(&Bs[q * 8]), 16, 0, 0);
        }
        __syncthreads();
#pragma unroll
        for (int kk = 0; kk < 2; ++kk) {
            bf16x8 a[4], b[4];
            const int cb = kk * 4 + (lane >> 4);
#pragma unroll
            for (int i = 0; i < 4; ++i) {
                int r = wm * 64 + i * 16 + (lane & 15);
                a[i] = *(const bf16x8*)&As[(r * 8 + (cb ^ (r & 7))) * 8];
            }
#pragma unroll
            for (int j = 0; j < 4; ++j) {
                int r = wn * 64 + j * 16 + (lane & 15);
                b[j] = *(const bf16x8*)&Bs[(r * 8 + (cb ^ (r & 7))) * 8];
            }
#pragma unroll
            for (int i = 0; i < 4; ++i)
#pragma unroll
                for (int j = 0; j < 4; ++j)
                    acc[i][j] = __builtin_amdgcn_mfma_f32_16x16x32_bf16(b[j], a[i], acc[i][j], 0, 0, 0);
        }
    }

    const int quad = lane >> 4;
#pragma unroll
    for (int i = 0; i < 4; ++i) {
        int row = rowBase + wm * 64 + i * 16 + (lane & 15);
        if (row >= Nrows) continue;
        float sc = 1.f;
        if (DEGB) sc = 1.f + (float)deg[row];
#pragma unroll
        for (int j = 0; j < 4; ++j) {
            int colb = nBase + wn * 64 + j * 16 + quad * 4;
            float4 bv = (colb < Mvalid) ? *(const float4*)(bias + colb)
                                        : (float4){0.f, 0.f, 0.f, 0.f};
            float v0 = acc[i][j][0] + sc * bv.x;
            float v1 = acc[i][j][1] + sc * bv.y;
            float v2 = acc[i][j][2] + sc * bv.z;
            float v3 = acc[i][j][3] + sc * bv.w;
            if (RELU) {
                v0 = v0 > 0.f ? v0 : 0.f; v1 = v1 > 0.f ? v1 : 0.f;
                v2 = v2 > 0.f ? v2 : 0.f; v3 = v3 > 0.f ? v3 : 0.f;
            }
            if (OUT_BF) {
                ushort4 o; o.x = f2bf(v0); o.y = f2bf(v1); o.z = f2bf(v2); o.w = f2bf(v3);
                *(ushort4*)(outB + (size_t)row * Mp + colb) = o;
            }
            if (OUT_F32) {
                if (colb < Mvalid)
                    *(float4*)(outF + (size_t)row * Mvalid + colb) = (float4){v0, v1, v2, v3};
            }
        }
    }
}

template <bool RELU, bool OUT_BF, bool OUT_F32, bool DEGB, int MT>
__global__ __launch_bounds__(256) void rg_gemm(
    const unsigned short* __restrict__ A, const unsigned short* __restrict__ Bt,
    const float* __restrict__ bias, const int* __restrict__ deg, int Mvalid,
    unsigned short* __restrict__ outB, float* __restrict__ outF,
    int Nrows, int Kp, int Mp, int gN)
{
    gemm_body<RELU, OUT_BF, OUT_F32, DEGB, MT>(blockIdx.x, A, Bt, bias, deg,
                                               Mvalid, outB, outF, Nrows, Kp, Mp, gN);
}

// ---------------- 256x256 2-phase/K-tile GEMM body (R11) --------------------
// 8 waves = 2(wm) x 4(wn); per wave 128x64 output, acc[8][4] f32x4.
// Phase ph of K-tile a computes quadrant rows [ph*128,+128) over all 256 cols
// (32 MFMA). Frags: phase0 reads A-h0 (8x b128) + both B halves (8x b128);
// phase1 reads A-h1 only (8x), reuses B regs. Staging: ph0 stages h1(a+1),
// ph1 stages h0(a+2) + vmcnt(4) (oldest 8 of 12 = tile a+1 landed).
template <bool RELU, int MT>
__device__ __forceinline__ void gemm256_body(
    int bid,
    const unsigned short* __restrict__ A, const unsigned short* __restrict__ Bt,
    const float* __restrict__ bias, unsigned short* __restrict__ outB,
    int Nrows, int NrowsPad, int Kp, int Mp, int gN2)
{
    __shared__ __align__(16) unsigned short As[2][2][128 * 64];  // [slot][half]
    __shared__ __align__(16) unsigned short Bs[2][2][128 * 64];

    int xcd = bid & 7;
    int slotb = bid >> 3;
    int c = slotb % MT;
    int rsub = slotb / MT;
    int rt = rsub * 8 + xcd;
    if (rt >= gN2) return;
    const int rowBase = rt * 256;
    const int nBase   = c * 256;

    const int tid  = threadIdx.x;
    const int lane = tid & 63;
    const int w    = tid >> 6;      // 0..7
    const int wm   = w & 1;         // 2 row-waves
    const int wn   = w >> 1;        // 4 col-waves
    const int lane15 = lane & 15;
    const int laneq  = lane >> 4;

    f32x4 acc[8][4];
#pragma unroll
    for (int i = 0; i < 8; ++i)
#pragma unroll
        for (int j = 0; j < 4; ++j) acc[i][j] = (f32x4){0.f, 0.f, 0.f, 0.f};

    const int nkt = Kp >> 6;        // 8 or 16 here

    // stage one 128x64 half-tile (2 x global_load_lds / thread, 16 KB)
    auto stageA = [&](int t, int hf) {
        const int k0 = t << 6;
        unsigned short* dst = &As[t & 1][hf][0];
#pragma unroll
        for (int ld = 0; ld < 2; ++ld) {
            int q   = ld * 512 + tid;        // chunk 0..1023
            int r   = q >> 3;                // local row 0..127
            int cbg = (q & 7) ^ (r & 7);
            int grow = rowBase + hf * 128 + r;
            grow = grow < NrowsPad ? grow : NrowsPad - 1;   // last-tile clamp
            const unsigned short* gp = A + (size_t)grow * Kp + k0 + cbg * 8;
            __builtin_amdgcn_global_load_lds(
                (const __attribute__((address_space(1))) void*)gp,
                (__attribute__((address_space(3))) void*)(dst + q * 8), 16, 0, 0);
        }
    };
    auto stageB = [&](int t, int hf) {
        const int k0 = t << 6;
        unsigned short* dst = &Bs[t & 1][hf][0];
#pragma unroll
        for (int ld = 0; ld < 2; ++ld) {
            int q   = ld * 512 + tid;
            int r   = q >> 3;
            int cbg = (q & 7) ^ (r & 7);
            const unsigned short* gp = Bt + (size_t)(nBase + hf * 128 + r) * Kp + k0 + cbg * 8;
            __builtin_amdgcn_global_load_lds(
                (const __attribute__((address_space(1))) void*)gp,
                (__attribute__((address_space(3))) void*)(dst + q * 8), 16, 0, 0);
        }
    };

    bf16x8 av[4][2];        // current row-half A frags
    bf16x8 bv[2][2][2];     // [nh][j][kk] -- whole K-tile of B, reused in ph1

    auto phase = [&](int a, int ph) {
        const int slot = a & 1;
        // A frags for row-half ph
#pragma unroll
        for (int i = 0; i < 4; ++i) {
            int lr = wm * 64 + i * 16 + lane15;
#pragma unroll
            for (int kk = 0; kk < 2; ++kk) {
                int cb = kk * 4 + laneq;
                av[i][kk] = *(const bf16x8*)&As[slot][ph][(lr * 8 + (cb ^ (lr & 7))) * 8];
            }
        }
        if (ph == 0) {
            // both B halves once per K-tile
#pragma unroll
            for (int nh = 0; nh < 2; ++nh)
#pragma unroll
                for (int j = 0; j < 2; ++j) {
                    int lr = wn * 32 + j * 16 + lane15;
#pragma unroll
                    for (int kk = 0; kk < 2; ++kk) {
                        int cb = kk * 4 + laneq;
                        bv[nh][j][kk] = *(const bf16x8*)&Bs[slot][nh][(lr * 8 + (cb ^ (lr & 7))) * 8];
                    }
                }
            if (a + 1 < nkt) { stageA(a + 1, 1); stageB(a + 1, 1); }
        } else {
            if (a + 2 < nkt) {
                stageA(a + 2, 0); stageB(a + 2, 0);
                asm volatile("s_waitcnt vmcnt(4)" ::: "memory");   // tile a+1 landed
            } else if (a + 1 < nkt) {
                asm volatile("s_waitcnt vmcnt(0)" ::: "memory");   // tail drain
            }
        }
        __builtin_amdgcn_sched_barrier(0);
        __builtin_amdgcn_s_barrier();
        asm volatile("s_waitcnt lgkmcnt(0)" ::: "memory");
        __builtin_amdgcn_sched_barrier(0);
        __builtin_amdgcn_s_setprio(1);
#pragma unroll
        for (int nh = 0; nh < 2; ++nh)
#pragma unroll
            for (int i = 0; i < 4; ++i)
#pragma unroll
                for (int j = 0; j < 2; ++j)
#pragma unroll
                    for (int kk = 0; kk < 2; ++kk)
                        acc[ph * 4 + i][nh * 2 + j] = __builtin_amdgcn_mfma_f32_16x16x32_bf16(
                            bv[nh][j][kk], av[i][kk], acc[ph * 4 + i][nh * 2 + j], 0, 0, 0);
        __builtin_amdgcn_s_setprio(0);
        __builtin_amdgcn_sched_barrier(0);
        __builtin_amdgcn_s_barrier();
    };

    // prologue: t0 complete + h0 of t1 (12 loads); vmcnt(4) -> t0 ready
    stageA(0, 0); stageB(0, 0); stageA(0, 1); stageB(0, 1);
    stageA(1, 0); stageB(1, 0);
    asm volatile("s_waitcnt vmcnt(4)" ::: "memory");
    __builtin_amdgcn_sched_barrier(0);
    __builtin_amdgcn_s_barrier();
    __builtin_amdgcn_sched_barrier(0);

    for (int a = 0; a < nkt; ++a) {
        phase(a, 0);
        phase(a, 1);
    }

    // epilogue (swapped layout): row from lane, 4 consecutive cols from regs
    const int quad = lane >> 4;
#pragma unroll
    for (int mi = 0; mi < 8; ++mi) {
        int row = rowBase + ((mi >> 2) * 2 + wm) * 64 + (mi & 3) * 16 + (lane & 15);
        if (row >= Nrows) continue;
#pragma unroll
        for (int nj = 0; nj < 4; ++nj) {
            int colb = nBase + (nj >> 1) * 128 + wn * 32 + (nj & 1) * 16 + quad * 4;
            float4 bvv = *(const float4*)(bias + colb);
            float v0 = acc[mi][nj][0] + bvv.x;
            float v1 = acc[mi][nj][1] + bvv.y;
            float v2 = acc[mi][nj][2] + bvv.z;
            float v3 = acc[mi][nj][3] + bvv.w;
            if (RELU) {
                v0 = v0 > 0.f ? v0 : 0.f; v1 = v1 > 0.f ? v1 : 0.f;
                v2 = v2 > 0.f ? v2 : 0.f; v3 = v3 > 0.f ? v3 : 0.f;
            }
            ushort4 o; o.x = f2bf(v0); o.y = f2bf(v1); o.z = f2bf(v2); o.w = f2bf(v3);
            *(ushort4*)(outB + (size_t)row * Mp + colb) = o;
        }
    }
}

template <bool RELU, int MT>
__global__ __launch_bounds__(512, 2) void rg_gemm256(
    const unsigned short* __restrict__ A, const unsigned short* __restrict__ Bt,
    const float* __restrict__ bias, unsigned short* __restrict__ outB,
    int Nrows, int NrowsPad, int Kp, int Mp, int gN2)
{
    gemm256_body<RELU, MT>(blockIdx.x, A, Bt, bias, outB, Nrows, NrowsPad, Kp, Mp, gN2);
}

// L1 GEMM (256x256) + edge scatter in one dispatch.
__global__ __launch_bounds__(512, 2) void rg_gemm256_l1_scatter(
    const unsigned short* __restrict__ A, const unsigned short* __restrict__ Bt,
    const float* __restrict__ bias, unsigned short* __restrict__ outB,
    int Nrows, int NrowsPad, int Kp, int Mp, int gN2,
    int gemmBlocks, const int* __restrict__ ei, int E,
    int* __restrict__ cursor, int* __restrict__ cols)
{
    int bid = blockIdx.x;
    if (bid < gemmBlocks) {
        gemm256_body<true, 4>(bid, A, Bt, bias, outB, Nrows, NrowsPad, Kp, Mp, gN2);
    } else {
        int e = (bid - gemmBlocks) * 512 + threadIdx.x;
        if (e < E) {
            int d = ei[E + e];
            int p = atomicAdd(&cursor[d], 1);
            cols[p] = ei[e];
        }
    }
}

// ---------------- merged scan (3 dispatches -> 1) ---------------------------
__device__ __forceinline__ void rg_gridbar(int* bar, int nb, int phase) {
    __syncthreads();
    if (threadIdx.x == 0) {
        __threadfence();
        atomicAdd(bar, 1);
        int target = phase * nb;
        while (__hip_atomic_load(bar, __ATOMIC_RELAXED, __HIP_MEMORY_SCOPE_AGENT) < target) {}
        __threadfence();
    }
    __syncthreads();
}

__global__ __launch_bounds__(1024) void rg_scan_all(
    const int* __restrict__ cnt, int* __restrict__ rowptr, int* __restrict__ cursor,
    int* __restrict__ bsums, int* bar, int Nn, int E, int nb)
{
    __shared__ int sd[1024];
    const int tid = threadIdx.x;
    const int bid = blockIdx.x;
    const int i   = bid * 1024 + tid;

    int v = (i < Nn) ? cnt[i] : 0;
    sd[tid] = v;
    __syncthreads();
    for (int off = 1; off < 1024; off <<= 1) {
        int t = (tid >= off) ? sd[tid - off] : 0;
        __syncthreads();
        sd[tid] += t;
        __syncthreads();
    }
    if (tid == 1023) bsums[bid] = sd[1023];
    rg_gridbar(bar, nb, 1);

    if (bid == 0 && tid < 64) {
        int bv = (tid < nb) ? bsums[tid] : 0;
        int incl = bv;
#pragma unroll
        for (int off = 1; off < 64; off <<= 1) {
            int t = __shfl_up(incl, off, 64);
            if (tid >= off) incl += t;
        }
        if (tid < nb) bsums[tid] = incl - bv;
    }
    rg_gridbar(bar, nb, 2);

    if (i < Nn) {
        int ex = sd[tid] - v + bsums[bid];
        rowptr[i] = ex; cursor[i] = ex;
    }
    if (i == 0) rowptr[Nn] = E;
}

// ---------------- 80-dim aggregation ---------------------------------------
__global__ __launch_bounds__(256) void rg_agg80(
    const unsigned short* __restrict__ pf, const int* __restrict__ rowptr,
    const int* __restrict__ cols, unsigned short* __restrict__ s, int Nn)
{
    int node = blockIdx.x * 4 + (threadIdx.x >> 6);
    if (node >= Nn) return;
    int lane = threadIdx.x & 63;
    const unsigned* xp = (const unsigned*)pf;
    size_t off = (size_t)node * 64 + lane;
    unsigned u = xp[off];
    float a0 = bf2f(u & 0xffffu), a1 = bf2f(u >> 16);
    int beg = rowptr[node], end = rowptr[node + 1];
    int e = beg;
    for (; e + 8 <= end; e += 8) {
        unsigned v[8];
#pragma unroll
        for (int t = 0; t < 8; ++t) v[t] = xp[(size_t)cols[e + t] * 64 + lane];
#pragma unroll
        for (int t = 0; t < 8; ++t) { a0 += bf2f(v[t] & 0xffffu); a1 += bf2f(v[t] >> 16); }
    }
    for (; e < end; ++e) {
        unsigned v = xp[(size_t)cols[e] * 64 + lane];
        a0 += bf2f(v & 0xffffu); a1 += bf2f(v >> 16);
    }
    unsigned o = (unsigned)f2bf(a0) | ((unsigned)f2bf(a1) << 16);
    ((unsigned*)s)[off] = o;
}

// ---------------------------------------------------------------------------
extern "C" void kernel_launch(void* const* d_in, const int* in_sizes, int n_in,
                              void* d_out, int out_size, void* d_ws, size_t ws_size,
                              hipStream_t stream)
{
    const float* feat = (const float*)d_in[0];
    const int*   ei   = (const int*)d_in[1];
    const float* W1 = (const float*)d_in[2];  const float* b1 = (const float*)d_in[3];
    const float* W2 = (const float*)d_in[4];  const float* b2 = (const float*)d_in[5];
    const float* W3 = (const float*)d_in[6];  const float* b3 = (const float*)d_in[7];
    const float* W4 = (const float*)d_in[8];  const float* b4 = (const float*)d_in[9];
    const float* Wi = (const float*)d_in[10]; const float* bi = (const float*)d_in[11];
    const float* Wg1 = (const float*)d_in[12]; const float* bg1 = (const float*)d_in[13];
    const float* Wg2 = (const float*)d_in[14]; const float* bg2 = (const float*)d_in[15];
    const float* Wo = (const float*)d_in[16]; const float* bo = (const float*)d_in[17];

    const int N = in_sizes[0] / 512;   // 50000
    const int E = in_sizes[1] / 2;     // 800000
    const int gN = (N + 127) / 128;    // 391
    const int Npad = gN * 128;         // 50048

    char* ws = (char*)d_ws;
    size_t o = 0;
    auto alloc = [&](size_t bytes) { char* p = ws + o; o += (bytes + 255) & ~(size_t)255; return p; };
    unsigned short* bufA = (unsigned short*)alloc((size_t)Npad * 1024 * 2); // h1 / pf / g
    unsigned short* bufB = (unsigned short*)alloc((size_t)Npad * 1024 * 2); // h2 / r1
    unsigned short* bufC = (unsigned short*)alloc((size_t)Npad * 512 * 2);  // A0 / h3 / s / g2
    unsigned short* W1t = (unsigned short*)alloc((size_t)1024 * 512 * 2);
    unsigned short* W2t = (unsigned short*)alloc((size_t)1024 * 1024 * 2);
    unsigned short* W3t = (unsigned short*)alloc((size_t)512 * 1024 * 2);
    unsigned short* W4t = (unsigned short*)alloc((size_t)128 * 512 * 2);
    unsigned short* Wit = (unsigned short*)alloc((size_t)512 * 128 * 2);
    unsigned short* Wg1t = (unsigned short*)alloc((size_t)512 * 512 * 2);
    unsigned short* Wg2t = (unsigned short*)alloc((size_t)512 * 512 * 2);
    unsigned short* Wot = (unsigned short*)alloc((size_t)128 * 512 * 2);
    int* cnt    = (int*)alloc((size_t)(N + 64) * 4);
    int* bar    = cnt + N;
    int* rowptr = (int*)alloc((size_t)(N + 1) * 4);
    int* cursor = (int*)alloc((size_t)N * 4);
    int* cols   = (int*)alloc((size_t)E * 4);
    int* bsums  = (int*)alloc(256);

    float* out_mask = (float*)d_out;                  // [N,80]
    float* out_feat = (float*)d_out + (size_t)N * 80; // [N,80]

    // ---- merged preprocessing ----
    hipMemsetAsync(cnt, 0, (size_t)(N + 64) * 4, stream);
    {
        PreDescs d;
        const float* Ws[8]  = {W1, W2, W3, W4, Wi, Wg1, Wg2, Wo};
        unsigned short* Ts[8] = {W1t, W2t, W3t, W4t, Wit, Wg1t, Wg2t, Wot};
        int Ks[8]  = {512, 1024, 1024, 512, 80, 512, 512, 512};
        int Ms[8]  = {1024, 1024, 512, 80, 512, 512, 512, 80};
        int Kps[8] = {512, 1024, 1024, 512, 128, 512, 512, 512};
        int Mps[8] = {1024, 1024, 512, 128, 512, 512, 512, 128};
        int st = 0;
        for (int i = 0; i < 8; ++i) {
            d.W[i] = Ws[i]; d.Wt[i] = Ts[i];
            d.K[i] = Ks[i]; d.M[i] = Ms[i]; d.Kp[i] = Kps[i];
            d.ntx[i] = Mps[i] / 32;
            d.start[i] = st;
            st += (Mps[i] / 32) * (Kps[i] / 32);
        }
        d.tEnd = st;
        d.cEnd = st + (N * 512) / 1024;
        d.eEnd = d.cEnd + (E + 255) / 256;
        d.feat = feat; d.featb = bufC; d.nFeat = N * 512;
        d.ei = ei; d.E = E; d.cnt = cnt;
        rg_preprocess<<<d.eEnd, 256, 0, stream>>>(d);
    }

    // ---- CSR scan ----
    const int nb = (N + 1023) / 1024;   // 49
    rg_scan_all<<<nb, 1024, 0, stream>>>(cnt, rowptr, cursor, bsums, bar, N, E, nb);

    const int rg8 = ((gN + 7) / 8) * 8;         // 392 (128-tile grid unit)
    auto grid = [&](int MT) { return dim3(rg8 * MT); };
    const int gN2 = (N + 255) / 256;            // 196 (256-tile rows)
    const int rg256 = ((gN2 + 7) / 8) * 8;      // 200

    // L1: h1 = relu(A0 @ W1 + b1)   [N,1024]  (256^2) + edge scatter
    {
        const int gemmBlocks = rg256 * 4;            // 800
        const int scatBlocks = (E + 511) / 512;      // 1563
        rg_gemm256_l1_scatter<<<dim3(gemmBlocks + scatBlocks), 512, 0, stream>>>(
            bufC, W1t, b1, bufA, N, Npad, 512, 1024, gN2,
            gemmBlocks, ei, E, cursor, cols);
    }

    // L2: h2 = relu(h1 @ W2 + b2)   [N,1024]   (256^2)
    rg_gemm256<true, 4><<<dim3(rg256 * 4), 512, 0, stream>>>(bufA, W2t, b2, bufB, N, Npad, 1024, 1024, gN2);
    // L3: h3 = relu(h2 @ W3 + b3)   [N,512]    (256^2)
    rg_gemm256<true, 2><<<dim3(rg256 * 2), 512, 0, stream>>>(bufB, W3t, b3, bufC, N, Npad, 1024, 512, gN2);
    // L4: pf = h3 @ W4 + b4  -> fp32 out_feat + bf16 padded [N,128]  (128^2)
    rg_gemm<false, true, true, false, 1><<<grid(1), 256, 0, stream>>>(bufC, W4t, b4, nullptr, 80, bufA, out_feat, N, 512, 128, gN);

    // 80-dim aggregation: s = pf + segsum(pf[src]) -> bufC[:, :128]
    rg_agg80<<<(N + 3) / 4, 256, 0, stream>>>(bufA, rowptr, cols, bufC, N);

    // L5: g = s @ Win + (1+deg)*bin  [N,512]   (128^2, K=128)
    rg_gemm<false, true, false, true, 4><<<grid(4), 256, 0, stream>>>(bufC, Wit, bi, cnt, 512, bufA, nullptr, N, 128, 512, gN);
    // L6: r1 = relu(g @ Wg1 + bg1)  [N,512]    (256^2)
    rg_gemm256<true, 2><<<dim3(rg256 * 2), 512, 0, stream>>>(bufA, Wg1t, bg1, bufB, N, Npad, 512, 512, gN2);
    // L7: g2 = r1 @ Wg2 + bg2       [N,512]    (256^2)
    rg_gemm256<false, 2><<<dim3(rg256 * 2), 512, 0, stream>>>(bufB, Wg2t, bg2, bufC, N, Npad, 512, 512, gN2);
    // L8: mask = g2 @ Wout + bout -> fp32 out_mask   (128^2)
    rg_gemm<false, false, true, false, 1><<<grid(1), 256, 0, stream>>>(bufC, Wot, bo, nullptr, 80, nullptr, out_mask, N, 512, 128, gN);
}

// Round 5
// 758.065 us; speedup vs baseline: 1.1392x; 1.0375x over previous
//
#include <hip/hip_runtime.h>
#include <stdint.h>

// ---------------------------------------------------------------------------
// ResidueGraphModel: aanet_proj (512->1024->1024->512->80, ReLU) -> in_net
// (80->512) -> GIN sum-aggregation + MLP (512->512->512) -> out_net (512->80).
// R13: two attributable changes vs R12.
//  (1) L2 reverted to the 128x128 single-buffer body (measured: 140.9us vs
//      256^2's 156.6us). 256^2 2-phase keeps L1/L3/L6/L7 (R12 total ~= R8
//      total => those layers are not worse; keeps A/B clean).
//  (2) __launch_bounds__(256,4) on the 128^2 body: unified reg use was
//      VGPR76+AGPR64=140 -> 3 waves/SIMD (VGPR-capped, not LDS). True need
//      ~116 (64 acc + 32 frags + ~20 addr) fits a 128 budget -> 4 waves/SIMD
//      = 4 blocks/CU -> more cross-block overlap of the barrier-drain stall
//      (the mechanism that makes the 2-barrier structure work at all).
// Invariants: XOR-swizzled LDS (0 bank conflicts), operand-swapped MFMA
// (packed 8B C stores), XCD-grouped decode, aggregation before in_net,
// edge scatter riding in L1's dispatch.
// Outputs fp32: d_out = [peptide_mask (N*80) | peptide_feat (N*80)].
// ---------------------------------------------------------------------------

using bf16x8 = __attribute__((ext_vector_type(8))) short;
using f32x4  = __attribute__((ext_vector_type(4))) float;

__device__ inline unsigned short f2bf(float f) {
    union { float f; unsigned u; } v; v.f = f;
    unsigned u = v.u;
    u += 0x7FFFu + ((u >> 16) & 1u);   // RNE
    return (unsigned short)(u >> 16);
}
__device__ inline float bf2f(unsigned u16) {
    return __uint_as_float(u16 << 16);
}

// ------------- merged preprocessing ----------------------------------------
struct PreDescs {
    const float* W[8]; unsigned short* Wt[8];
    int K[8], M[8], Kp[8], ntx[8], start[8];
    int tEnd, cEnd, eEnd;
    const float* feat; unsigned short* featb; int nFeat;
    const int* ei; int E; int* cnt;
};

__global__ __launch_bounds__(256) void rg_preprocess(PreDescs d) {
    int b = blockIdx.x;
    int tid = threadIdx.x;
    if (b < d.tEnd) {
        __shared__ float t[32][33];
        int di = 0;
#pragma unroll
        for (int i = 1; i < 8; ++i) if (b >= d.start[i]) di = i;
        int local = b - d.start[di];
        int bx = local % d.ntx[di];
        int by = local / d.ntx[di];
        const float* W = d.W[di];
        unsigned short* Wt = d.Wt[di];
        int K = d.K[di], M = d.M[di], Kp = d.Kp[di];
        int mb = bx * 32, kb = by * 32;
        int tx = tid & 31, tg = tid >> 5;
#pragma unroll
        for (int p = 0; p < 4; ++p) {
            int r = tg + p * 8;
            int k = kb + r, m = mb + tx;
            t[r][tx] = (k < K && m < M) ? W[(size_t)k * M + m] : 0.f;
        }
        __syncthreads();
#pragma unroll
        for (int p = 0; p < 4; ++p) {
            int r = tg + p * 8;
            int mo = mb + r, ko = kb + tx;
            Wt[(size_t)mo * Kp + ko] = f2bf(t[tx][r]);
        }
    } else if (b < d.cEnd) {
        int i = ((b - d.tEnd) * 256 + tid) * 4;
        if (i + 3 < d.nFeat) {
            float4 v = *(const float4*)(d.feat + i);
            ushort4 o; o.x = f2bf(v.x); o.y = f2bf(v.y); o.z = f2bf(v.z); o.w = f2bf(v.w);
            *(ushort4*)(d.featb + i) = o;
        }
    } else {
        int e = (b - d.cEnd) * 256 + tid;
        if (e < d.E) atomicAdd(&d.cnt[d.ei[d.E + e]], 1);
    }
}

// ---------------- 128x128 GEMM body (R8, single-buffer) ---------------------
template <bool RELU, bool OUT_BF, bool OUT_F32, bool DEGB, int MT>
__device__ __forceinline__ void gemm_body(
    int bid,
    const unsigned short* __restrict__ A, const unsigned short* __restrict__ Bt,
    const float* __restrict__ bias, const int* __restrict__ deg, int Mvalid,
    unsigned short* __restrict__ outB, float* __restrict__ outF,
    int Nrows, int Kp, int Mp, int gN)
{
    __shared__ __align__(16) unsigned short As[128 * 64];
    __shared__ __align__(16) unsigned short Bs[128 * 64];

    int xcd = bid & 7;
    int slot = bid >> 3;
    int c = slot % MT;
    int rsub = slot / MT;
    int rt = rsub * 8 + xcd;
    if (rt >= gN) return;
    const int rowBase = rt * 128;
    const int nBase   = c * 128;

    const int tid  = threadIdx.x;
    const int lane = tid & 63;
    const int w    = tid >> 6;
    const int wm   = w & 1, wn = w >> 1;

    f32x4 acc[4][4];
#pragma unroll
    for (int i = 0; i < 4; ++i)
#pragma unroll
        for (int j = 0; j < 4; ++j) acc[i][j] = (f32x4){0.f, 0.f, 0.f, 0.f};

    const int nkt = Kp >> 6;
    for (int kt = 0; kt < nkt; ++kt) {
        __syncthreads();
        const int k0 = kt * 64;
#pragma unroll
        for (int i = 0; i < 4; ++i) {
            int q   = i * 256 + tid;
            int r   = q >> 3;
            int cbg = (q & 7) ^ (r & 7);
            const unsigned short* gp = A + (size_t)(rowBase + r) * Kp + k0 + cbg * 8;
            __builtin_amdgcn_global_load_lds(
                (const __attribute__((address_space(1))) void*)gp,
                (__attribute__((address_space(3))) void*)(&As[q * 8]), 16, 0, 0);
        }
#pragma unroll
        for (int i = 0; i < 4; ++i) {
            int q   = i * 256 + tid;
            int r   = q >> 3;
            int cbg = (q & 7) ^ (r & 7);
            const unsigned short* gp = Bt + (size_t)(nBase + r) * Kp + k0 + cbg * 8;
            __builtin_amdgcn_global_load_lds(
                (const __attribute__((address_space(1))) void*)gp,
                (__attribute__((address_space(3))) void*)(&Bs[q * 8]), 16, 0, 0);
        }
        __syncthreads();
#pragma unroll
        for (int kk = 0; kk < 2; ++kk) {
            bf16x8 a[4], b[4];
            const int cb = kk * 4 + (lane >> 4);
#pragma unroll
            for (int i = 0; i < 4; ++i) {
                int r = wm * 64 + i * 16 + (lane & 15);
                a[i] = *(const bf16x8*)&As[(r * 8 + (cb ^ (r & 7))) * 8];
            }
#pragma unroll
            for (int j = 0; j < 4; ++j) {
                int r = wn * 64 + j * 16 + (lane & 15);
                b[j] = *(const bf16x8*)&Bs[(r * 8 + (cb ^ (r & 7))) * 8];
            }
#pragma unroll
            for (int i = 0; i < 4; ++i)
#pragma unroll
                for (int j = 0; j < 4; ++j)
                    acc[i][j] = __builtin_amdgcn_mfma_f32_16x16x32_bf16(b[j], a[i], acc[i][j], 0, 0, 0);
        }
    }

    const int quad = lane >> 4;
#pragma unroll
    for (int i = 0; i < 4; ++i) {
        int row = rowBase + wm * 64 + i * 16 + (lane & 15);
        if (row >= Nrows) continue;
        float sc = 1.f;
        if (DEGB) sc = 1.f + (float)deg[row];
#pragma unroll
        for (int j = 0; j < 4; ++j) {
            int colb = nBase + wn * 64 + j * 16 + quad * 4;
            float4 bv = (colb < Mvalid) ? *(const float4*)(bias + colb)
                                        : (float4){0.f, 0.f, 0.f, 0.f};
            float v0 = acc[i][j][0] + sc * bv.x;
            float v1 = acc[i][j][1] + sc * bv.y;
            float v2 = acc[i][j][2] + sc * bv.z;
            float v3 = acc[i][j][3] + sc * bv.w;
            if (RELU) {
                v0 = v0 > 0.f ? v0 : 0.f; v1 = v1 > 0.f ? v1 : 0.f;
                v2 = v2 > 0.f ? v2 : 0.f; v3 = v3 > 0.f ? v3 : 0.f;
            }
            if (OUT_BF) {
                ushort4 o; o.x = f2bf(v0); o.y = f2bf(v1); o.z = f2bf(v2); o.w = f2bf(v3);
                *(ushort4*)(outB + (size_t)row * Mp + colb) = o;
            }
            if (OUT_F32) {
                if (colb < Mvalid)
                    *(float4*)(outF + (size_t)row * Mvalid + colb) = (float4){v0, v1, v2, v3};
            }
        }
    }
}

template <bool RELU, bool OUT_BF, bool OUT_F32, bool DEGB, int MT>
__global__ __launch_bounds__(256, 4) void rg_gemm(
    const unsigned short* __restrict__ A, const unsigned short* __restrict__ Bt,
    const float* __restrict__ bias, const int* __restrict__ deg, int Mvalid,
    unsigned short* __restrict__ outB, float* __restrict__ outF,
    int Nrows, int Kp, int Mp, int gN)
{
    gemm_body<RELU, OUT_BF, OUT_F32, DEGB, MT>(blockIdx.x, A, Bt, bias, deg,
                                               Mvalid, outB, outF, Nrows, Kp, Mp, gN);
}

// ---------------- 256x256 2-phase/K-tile GEMM body (R11/R12) ----------------
// 8 waves = 2(wm) x 4(wn); per wave 128x64 output, acc[8][4] f32x4.
// Phase ph of K-tile a computes quadrant rows [ph*128,+128) over all 256 cols
// (32 MFMA). Frags: phase0 reads A-h0 (8x b128) + both B halves (8x b128);
// phase1 reads A-h1 only (8x), reuses B regs. Staging: ph0 stages h1(a+1),
// ph1 stages h0(a+2) + vmcnt(4) (oldest 8 of 12 = tile a+1 landed).
template <bool RELU, int MT>
__device__ __forceinline__ void gemm256_body(
    int bid,
    const unsigned short* __restrict__ A, const unsigned short* __restrict__ Bt,
    const float* __restrict__ bias, unsigned short* __restrict__ outB,
    int Nrows, int NrowsPad, int Kp, int Mp, int gN2)
{
    __shared__ __align__(16) unsigned short As[2][2][128 * 64];  // [slot][half]
    __shared__ __align__(16) unsigned short Bs[2][2][128 * 64];

    int xcd = bid & 7;
    int slotb = bid >> 3;
    int c = slotb % MT;
    int rsub = slotb / MT;
    int rt = rsub * 8 + xcd;
    if (rt >= gN2) return;
    const int rowBase = rt * 256;
    const int nBase   = c * 256;

    const int tid  = threadIdx.x;
    const int lane = tid & 63;
    const int w    = tid >> 6;      // 0..7
    const int wm   = w & 1;         // 2 row-waves
    const int wn   = w >> 1;        // 4 col-waves
    const int lane15 = lane & 15;
    const int laneq  = lane >> 4;

    f32x4 acc[8][4];
#pragma unroll
    for (int i = 0; i < 8; ++i)
#pragma unroll
        for (int j = 0; j < 4; ++j) acc[i][j] = (f32x4){0.f, 0.f, 0.f, 0.f};

    const int nkt = Kp >> 6;        // 8 or 16 here

    // stage one 128x64 half-tile (2 x global_load_lds / thread, 16 KB)
    auto stageA = [&](int t, int hf) {
        const int k0 = t << 6;
        unsigned short* dst = &As[t & 1][hf][0];
#pragma unroll
        for (int ld = 0; ld < 2; ++ld) {
            int q   = ld * 512 + tid;        // chunk 0..1023
            int r   = q >> 3;                // local row 0..127
            int cbg = (q & 7) ^ (r & 7);
            int grow = rowBase + hf * 128 + r;
            grow = grow < NrowsPad ? grow : NrowsPad - 1;   // last-tile clamp
            const unsigned short* gp = A + (size_t)grow * Kp + k0 + cbg * 8;
            __builtin_amdgcn_global_load_lds(
                (const __attribute__((address_space(1))) void*)gp,
                (__attribute__((address_space(3))) void*)(dst + q * 8), 16, 0, 0);
        }
    };
    auto stageB = [&](int t, int hf) {
        const int k0 = t << 6;
        unsigned short* dst = &Bs[t & 1][hf][0];
#pragma unroll
        for (int ld = 0; ld < 2; ++ld) {
            int q   = ld * 512 + tid;
            int r   = q >> 3;
            int cbg = (q & 7) ^ (r & 7);
            const unsigned short* gp = Bt + (size_t)(nBase + hf * 128 + r) * Kp + k0 + cbg * 8;
            __builtin_amdgcn_global_load_lds(
                (const __attribute__((address_space(1))) void*)gp,
                (__attribute__((address_space(3))) void*)(dst + q * 8), 16, 0, 0);
        }
    };

    bf16x8 av[4][2];        // current row-half A frags
    bf16x8 bv[2][2][2];     // [nh][j][kk] -- whole K-tile of B, reused in ph1

    auto phase = [&](int a, int ph) {
        const int slot = a & 1;
        // A frags for row-half ph
#pragma unroll
        for (int i = 0; i < 4; ++i) {
            int lr = wm * 64 + i * 16 + lane15;
#pragma unroll
            for (int kk = 0; kk < 2; ++kk) {
                int cb = kk * 4 + laneq;
                av[i][kk] = *(const bf16x8*)&As[slot][ph][(lr * 8 + (cb ^ (lr & 7))) * 8];
            }
        }
        if (ph == 0) {
            // both B halves once per K-tile
#pragma unroll
            for (int nh = 0; nh < 2; ++nh)
#pragma unroll
                for (int j = 0; j < 2; ++j) {
                    int lr = wn * 32 + j * 16 + lane15;
#pragma unroll
                    for (int kk = 0; kk < 2; ++kk) {
                        int cb = kk * 4 + laneq;
                        bv[nh][j][kk] = *(const bf16x8*)&Bs[slot][nh][(lr * 8 + (cb ^ (lr & 7))) * 8];
                    }
                }
            if (a + 1 < nkt) { stageA(a + 1, 1); stageB(a + 1, 1); }
        } else {
            if (a + 2 < nkt) {
                stageA(a + 2, 0); stageB(a + 2, 0);
                asm volatile("s_waitcnt vmcnt(4)" ::: "memory");   // tile a+1 landed
            } else if (a + 1 < nkt) {
                asm volatile("s_waitcnt vmcnt(0)" ::: "memory");   // tail drain
            }
        }
        __builtin_amdgcn_sched_barrier(0);
        __builtin_amdgcn_s_barrier();
        asm volatile("s_waitcnt lgkmcnt(0)" ::: "memory");
        __builtin_amdgcn_sched_barrier(0);
        __builtin_amdgcn_s_setprio(1);
#pragma unroll
        for (int nh = 0; nh < 2; ++nh)
#pragma unroll
            for (int i = 0; i < 4; ++i)
#pragma unroll
                for (int j = 0; j < 2; ++j)
#pragma unroll
                    for (int kk = 0; kk < 2; ++kk)
                        acc[ph * 4 + i][nh * 2 + j] = __builtin_amdgcn_mfma_f32_16x16x32_bf16(
                            bv[nh][j][kk], av[i][kk], acc[ph * 4 + i][nh * 2 + j], 0, 0, 0);
        __builtin_amdgcn_s_setprio(0);
        __builtin_amdgcn_sched_barrier(0);
        __builtin_amdgcn_s_barrier();
    };

    // prologue: t0 complete + h0 of t1 (12 loads); vmcnt(4) -> t0 ready
    stageA(0, 0); stageB(0, 0); stageA(0, 1); stageB(0, 1);
    stageA(1, 0); stageB(1, 0);
    asm volatile("s_waitcnt vmcnt(4)" ::: "memory");
    __builtin_amdgcn_sched_barrier(0);
    __builtin_amdgcn_s_barrier();
    __builtin_amdgcn_sched_barrier(0);

    for (int a = 0; a < nkt; ++a) {
        phase(a, 0);
        phase(a, 1);
    }

    // epilogue (swapped layout): row from lane, 4 consecutive cols from regs
    const int quad = lane >> 4;
#pragma unroll
    for (int mi = 0; mi < 8; ++mi) {
        int row = rowBase + ((mi >> 2) * 2 + wm) * 64 + (mi & 3) * 16 + (lane & 15);
        if (row >= Nrows) continue;
#pragma unroll
        for (int nj = 0; nj < 4; ++nj) {
            int colb = nBase + (nj >> 1) * 128 + wn * 32 + (nj & 1) * 16 + quad * 4;
            float4 bvv = *(const float4*)(bias + colb);
            float v0 = acc[mi][nj][0] + bvv.x;
            float v1 = acc[mi][nj][1] + bvv.y;
            float v2 = acc[mi][nj][2] + bvv.z;
            float v3 = acc[mi][nj][3] + bvv.w;
            if (RELU) {
                v0 = v0 > 0.f ? v0 : 0.f; v1 = v1 > 0.f ? v1 : 0.f;
                v2 = v2 > 0.f ? v2 : 0.f; v3 = v3 > 0.f ? v3 : 0.f;
            }
            ushort4 o; o.x = f2bf(v0); o.y = f2bf(v1); o.z = f2bf(v2); o.w = f2bf(v3);
            *(ushort4*)(outB + (size_t)row * Mp + colb) = o;
        }
    }
}

template <bool RELU, int MT>
__global__ __launch_bounds__(512, 2) void rg_gemm256(
    const unsigned short* __restrict__ A, const unsigned short* __restrict__ Bt,
    const float* __restrict__ bias, unsigned short* __restrict__ outB,
    int Nrows, int NrowsPad, int Kp, int Mp, int gN2)
{
    gemm256_body<RELU, MT>(blockIdx.x, A, Bt, bias, outB, Nrows, NrowsPad, Kp, Mp, gN2);
}

// L1 GEMM (256x256) + edge scatter in one dispatch.
__global__ __launch_bounds__(512, 2) void rg_gemm256_l1_scatter(
    const unsigned short* __restrict__ A, const unsigned short* __restrict__ Bt,
    const float* __restrict__ bias, unsigned short* __restrict__ outB,
    int Nrows, int NrowsPad, int Kp, int Mp, int gN2,
    int gemmBlocks, const int* __restrict__ ei, int E,
    int* __restrict__ cursor, int* __restrict__ cols)
{
    int bid = blockIdx.x;
    if (bid < gemmBlocks) {
        gemm256_body<true, 4>(bid, A, Bt, bias, outB, Nrows, NrowsPad, Kp, Mp, gN2);
    } else {
        int e = (bid - gemmBlocks) * 512 + threadIdx.x;
        if (e < E) {
            int d = ei[E + e];
            int p = atomicAdd(&cursor[d], 1);
            cols[p] = ei[e];
        }
    }
}

// ---------------- merged scan (3 dispatches -> 1) ---------------------------
__device__ __forceinline__ void rg_gridbar(int* bar, int nb, int phase) {
    __syncthreads();
    if (threadIdx.x == 0) {
        __threadfence();
        atomicAdd(bar, 1);
        int target = phase * nb;
        while (__hip_atomic_load(bar, __ATOMIC_RELAXED, __HIP_MEMORY_SCOPE_AGENT) < target) {}
        __threadfence();
    }
    __syncthreads();
}

__global__ __launch_bounds__(1024) void rg_scan_all(
    const int* __restrict__ cnt, int* __restrict__ rowptr, int* __restrict__ cursor,
    int* __restrict__ bsums, int* bar, int Nn, int E, int nb)
{
    __shared__ int sd[1024];
    const int tid = threadIdx.x;
    const int bid = blockIdx.x;
    const int i   = bid * 1024 + tid;

    int v = (i < Nn) ? cnt[i] : 0;
    sd[tid] = v;
    __syncthreads();
    for (int off = 1; off < 1024; off <<= 1) {
        int t = (tid >= off) ? sd[tid - off] : 0;
        __syncthreads();
        sd[tid] += t;
        __syncthreads();
    }
    if (tid == 1023) bsums[bid] = sd[1023];
    rg_gridbar(bar, nb, 1);

    if (bid == 0 && tid < 64) {
        int bv = (tid < nb) ? bsums[tid] : 0;
        int incl = bv;
#pragma unroll
        for (int off = 1; off < 64; off <<= 1) {
            int t = __shfl_up(incl, off, 64);
            if (tid >= off) incl += t;
        }
        if (tid < nb) bsums[tid] = incl - bv;
    }
    rg_gridbar(bar, nb, 2);

    if (i < Nn) {
        int ex = sd[tid] - v + bsums[bid];
        rowptr[i] = ex; cursor[i] = ex;
    }
    if (i == 0) rowptr[Nn] = E;
}

// ---------------- 80-dim aggregation ---------------------------------------
__global__ __launch_bounds__(256) void rg_agg80(
    const unsigned short* __restrict__ pf, const int* __restrict__ rowptr,
    const int* __restrict__ cols, unsigned short* __restrict__ s, int Nn)
{
    int node = blockIdx.x * 4 + (threadIdx.x >> 6);
    if (node >= Nn) return;
    int lane = threadIdx.x & 63;
    const unsigned* xp = (const unsigned*)pf;
    size_t off = (size_t)node * 64 + lane;
    unsigned u = xp[off];
    float a0 = bf2f(u & 0xffffu), a1 = bf2f(u >> 16);
    int beg = rowptr[node], end = rowptr[node + 1];
    int e = beg;
    for (; e + 8 <= end; e += 8) {
        unsigned v[8];
#pragma unroll
        for (int t = 0; t < 8; ++t) v[t] = xp[(size_t)cols[e + t] * 64 + lane];
#pragma unroll
        for (int t = 0; t < 8; ++t) { a0 += bf2f(v[t] & 0xffffu); a1 += bf2f(v[t] >> 16); }
    }
    for (; e < end; ++e) {
        unsigned v = xp[(size_t)cols[e] * 64 + lane];
        a0 += bf2f(v & 0xffffu); a1 += bf2f(v >> 16);
    }
    unsigned o = (unsigned)f2bf(a0) | ((unsigned)f2bf(a1) << 16);
    ((unsigned*)s)[off] = o;
}

// ---------------------------------------------------------------------------
extern "C" void kernel_launch(void* const* d_in, const int* in_sizes, int n_in,
                              void* d_out, int out_size, void* d_ws, size_t ws_size,
                              hipStream_t stream)
{
    const float* feat = (const float*)d_in[0];
    const int*   ei   = (const int*)d_in[1];
    const float* W1 = (const float*)d_in[2];  const float* b1 = (const float*)d_in[3];
    const float* W2 = (const float*)d_in[4];  const float* b2 = (const float*)d_in[5];
    const float* W3 = (const float*)d_in[6];  const float* b3 = (const float*)d_in[7];
    const float* W4 = (const float*)d_in[8];  const float* b4 = (const float*)d_in[9];
    const float* Wi = (const float*)d_in[10]; const float* bi = (const float*)d_in[11];
    const float* Wg1 = (const float*)d_in[12]; const float* bg1 = (const float*)d_in[13];
    const float* Wg2 = (const float*)d_in[14]; const float* bg2 = (const float*)d_in[15];
    const float* Wo = (const float*)d_in[16]; const float* bo = (const float*)d_in[17];

    const int N = in_sizes[0] / 512;   // 50000
    const int E = in_sizes[1] / 2;     // 800000
    const int gN = (N + 127) / 128;    // 391
    const int Npad = gN * 128;         // 50048

    char* ws = (char*)d_ws;
    size_t o = 0;
    auto alloc = [&](size_t bytes) { char* p = ws + o; o += (bytes + 255) & ~(size_t)255; return p; };
    unsigned short* bufA = (unsigned short*)alloc((size_t)Npad * 1024 * 2); // h1 / pf / g
    unsigned short* bufB = (unsigned short*)alloc((size_t)Npad * 1024 * 2); // h2 / r1
    unsigned short* bufC = (unsigned short*)alloc((size_t)Npad * 512 * 2);  // A0 / h3 / s / g2
    unsigned short* W1t = (unsigned short*)alloc((size_t)1024 * 512 * 2);
    unsigned short* W2t = (unsigned short*)alloc((size_t)1024 * 1024 * 2);
    unsigned short* W3t = (unsigned short*)alloc((size_t)512 * 1024 * 2);
    unsigned short* W4t = (unsigned short*)alloc((size_t)128 * 512 * 2);
    unsigned short* Wit = (unsigned short*)alloc((size_t)512 * 128 * 2);
    unsigned short* Wg1t = (unsigned short*)alloc((size_t)512 * 512 * 2);
    unsigned short* Wg2t = (unsigned short*)alloc((size_t)512 * 512 * 2);
    unsigned short* Wot = (unsigned short*)alloc((size_t)128 * 512 * 2);
    int* cnt    = (int*)alloc((size_t)(N + 64) * 4);
    int* bar    = cnt + N;
    int* rowptr = (int*)alloc((size_t)(N + 1) * 4);
    int* cursor = (int*)alloc((size_t)N * 4);
    int* cols   = (int*)alloc((size_t)E * 4);
    int* bsums  = (int*)alloc(256);

    float* out_mask = (float*)d_out;                  // [N,80]
    float* out_feat = (float*)d_out + (size_t)N * 80; // [N,80]

    // ---- merged preprocessing ----
    hipMemsetAsync(cnt, 0, (size_t)(N + 64) * 4, stream);
    {
        PreDescs d;
        const float* Ws[8]  = {W1, W2, W3, W4, Wi, Wg1, Wg2, Wo};
        unsigned short* Ts[8] = {W1t, W2t, W3t, W4t, Wit, Wg1t, Wg2t, Wot};
        int Ks[8]  = {512, 1024, 1024, 512, 80, 512, 512, 512};
        int Ms[8]  = {1024, 1024, 512, 80, 512, 512, 512, 80};
        int Kps[8] = {512, 1024, 1024, 512, 128, 512, 512, 512};
        int Mps[8] = {1024, 1024, 512, 128, 512, 512, 512, 128};
        int st = 0;
        for (int i = 0; i < 8; ++i) {
            d.W[i] = Ws[i]; d.Wt[i] = Ts[i];
            d.K[i] = Ks[i]; d.M[i] = Ms[i]; d.Kp[i] = Kps[i];
            d.ntx[i] = Mps[i] / 32;
            d.start[i] = st;
            st += (Mps[i] / 32) * (Kps[i] / 32);
        }
        d.tEnd = st;
        d.cEnd = st + (N * 512) / 1024;
        d.eEnd = d.cEnd + (E + 255) / 256;
        d.feat = feat; d.featb = bufC; d.nFeat = N * 512;
        d.ei = ei; d.E = E; d.cnt = cnt;
        rg_preprocess<<<d.eEnd, 256, 0, stream>>>(d);
    }

    // ---- CSR scan ----
    const int nb = (N + 1023) / 1024;   // 49
    rg_scan_all<<<nb, 1024, 0, stream>>>(cnt, rowptr, cursor, bsums, bar, N, E, nb);

    const int rg8 = ((gN + 7) / 8) * 8;         // 392 (128-tile grid unit)
    auto grid = [&](int MT) { return dim3(rg8 * MT); };
    const int gN2 = (N + 255) / 256;            // 196 (256-tile rows)
    const int rg256 = ((gN2 + 7) / 8) * 8;      // 200

    // L1: h1 = relu(A0 @ W1 + b1)   [N,1024]  (256^2) + edge scatter
    {
        const int gemmBlocks = rg256 * 4;            // 800
        const int scatBlocks = (E + 511) / 512;      // 1563
        rg_gemm256_l1_scatter<<<dim3(gemmBlocks + scatBlocks), 512, 0, stream>>>(
            bufC, W1t, b1, bufA, N, Npad, 512, 1024, gN2,
            gemmBlocks, ei, E, cursor, cols);
    }

    // L2: h2 = relu(h1 @ W2 + b2)   [N,1024]   (128^2 MT=8, bounds(256,4))
    rg_gemm<true, true, false, false, 8><<<grid(8), 256, 0, stream>>>(bufA, W2t, b2, nullptr, 1024, bufB, nullptr, N, 1024, 1024, gN);
    // L3: h3 = relu(h2 @ W3 + b3)   [N,512]    (256^2)
    rg_gemm256<true, 2><<<dim3(rg256 * 2), 512, 0, stream>>>(bufB, W3t, b3, bufC, N, Npad, 1024, 512, gN2);
    // L4: pf = h3 @ W4 + b4  -> fp32 out_feat + bf16 padded [N,128]  (128^2)
    rg_gemm<false, true, true, false, 1><<<grid(1), 256, 0, stream>>>(bufC, W4t, b4, nullptr, 80, bufA, out_feat, N, 512, 128, gN);

    // 80-dim aggregation: s = pf + segsum(pf[src]) -> bufC[:, :128]
    rg_agg80<<<(N + 3) / 4, 256, 0, stream>>>(bufA, rowptr, cols, bufC, N);

    // L5: g = s @ Win + (1+deg)*bin  [N,512]   (128^2, K=128)
    rg_gemm<false, true, false, true, 4><<<grid(4), 256, 0, stream>>>(bufC, Wit, bi, cnt, 512, bufA, nullptr, N, 128, 512, gN);
    // L6: r1 = relu(g @ Wg1 + bg1)  [N,512]    (256^2)
    rg_gemm256<true, 2><<<dim3(rg256 * 2), 512, 0, stream>>>(bufA, Wg1t, bg1, bufB, N, Npad, 512, 512, gN2);
    // L7: g2 = r1 @ Wg2 + bg2       [N,512]    (256^2)
    rg_gemm256<false, 2><<<dim3(rg256 * 2), 512, 0, stream>>>(bufB, Wg2t, bg2, bufC, N, Npad, 512, 512, gN2);
    // L8: mask = g2 @ Wout + bout -> fp32 out_mask   (128^2)
    rg_gemm<false, false, true, false, 1><<<grid(1), 256, 0, stream>>>(bufC, Wot, bo, nullptr, 80, nullptr, out_mask, N, 512, 128, gN);
}

// Round 6
// 702.126 us; speedup vs baseline: 1.2300x; 1.0797x over previous
//
#include <hip/hip_runtime.h>
#include <stdint.h>

// ---------------------------------------------------------------------------
// ResidueGraphModel: aanet_proj (512->1024->1024->512->80, ReLU) -> in_net
// (80->512) -> GIN sum-aggregation + MLP (512->512->512) -> out_net (512->80).
// R14: roll out the measured winner. R13 proved 128x128 + __launch_bounds__
// (256,4) beats the 256x256 2-phase port on the SAME layer (L2: ~128us vs
// 156.6us) and beats unbounded 128x128 (140.9us): the body was VGPR-capped
// at 3 waves/SIMD (76 VGPR + 64 AGPR = 140 unified); capping the allocator
// at 128 buys the 4th wave -> 4 blocks/CU of cross-block overlap. This round
// reverts ALL remaining 256^2 layers (L1+scatter, L3, L6, L7) to the R8
// 128x128 single-buffer structure with the (256,4) bound. 256^2 code deleted.
// Invariants: XOR-swizzled LDS (0 bank conflicts), operand-swapped MFMA
// (packed 8B C stores), XCD-grouped decode, row-padded A buffers (no clamp),
// aggregation before in_net (80-dim gather), edge scatter riding in L1.
// Outputs fp32: d_out = [peptide_mask (N*80) | peptide_feat (N*80)].
// ---------------------------------------------------------------------------

using bf16x8 = __attribute__((ext_vector_type(8))) short;
using f32x4  = __attribute__((ext_vector_type(4))) float;

__device__ inline unsigned short f2bf(float f) {
    union { float f; unsigned u; } v; v.f = f;
    unsigned u = v.u;
    u += 0x7FFFu + ((u >> 16) & 1u);   // RNE
    return (unsigned short)(u >> 16);
}
__device__ inline float bf2f(unsigned u16) {
    return __uint_as_float(u16 << 16);
}

// ------------- merged preprocessing ----------------------------------------
// Block ranges: [0, tEnd) -> weight transpose+convert (32x32 tiles, 256 thr)
//               [tEnd, cEnd) -> feat f32->bf16 convert (1024 elems/block)
//               [cEnd, eEnd) -> edge dst counting (256 edges/block)
struct PreDescs {
    const float* W[8]; unsigned short* Wt[8];
    int K[8], M[8], Kp[8], ntx[8], start[8];
    int tEnd, cEnd, eEnd;
    const float* feat; unsigned short* featb; int nFeat;
    const int* ei; int E; int* cnt;
};

__global__ __launch_bounds__(256) void rg_preprocess(PreDescs d) {
    int b = blockIdx.x;
    int tid = threadIdx.x;
    if (b < d.tEnd) {
        // transpose: W[K][M] f32 -> Wt[Mp][Kp] bf16 (pad with 0)
        __shared__ float t[32][33];
        int di = 0;
#pragma unroll
        for (int i = 1; i < 8; ++i) if (b >= d.start[i]) di = i;
        int local = b - d.start[di];
        int bx = local % d.ntx[di];
        int by = local / d.ntx[di];
        const float* W = d.W[di];
        unsigned short* Wt = d.Wt[di];
        int K = d.K[di], M = d.M[di], Kp = d.Kp[di];
        int mb = bx * 32, kb = by * 32;
        int tx = tid & 31, tg = tid >> 5;   // 8 rows per pass, 4 passes
#pragma unroll
        for (int p = 0; p < 4; ++p) {
            int r = tg + p * 8;             // tile row (k-dir)
            int k = kb + r, m = mb + tx;
            t[r][tx] = (k < K && m < M) ? W[(size_t)k * M + m] : 0.f;
        }
        __syncthreads();
#pragma unroll
        for (int p = 0; p < 4; ++p) {
            int r = tg + p * 8;             // tile row (m-dir)
            int mo = mb + r, ko = kb + tx;
            Wt[(size_t)mo * Kp + ko] = f2bf(t[tx][r]);
        }
    } else if (b < d.cEnd) {
        int i = ((b - d.tEnd) * 256 + tid) * 4;
        if (i + 3 < d.nFeat) {
            float4 v = *(const float4*)(d.feat + i);
            ushort4 o; o.x = f2bf(v.x); o.y = f2bf(v.y); o.z = f2bf(v.z); o.w = f2bf(v.w);
            *(ushort4*)(d.featb + i) = o;
        }
    } else {
        int e = (b - d.cEnd) * 256 + tid;
        if (e < d.E) atomicAdd(&d.cnt[d.ei[d.E + e]], 1);
    }
}

// ---------------- GEMM body: C[N,Mp] = act(A[N,Kp] @ Wt[Mp,Kp]^T + b) -------
// XOR swizzle: LDS chunk q (16B) of a tile row r holds global chunk
// (q&7)^(r&7); staging lane loads the matching global address, fragment
// reads apply the same XOR -> zero measured bank conflicts.
// Operand swap: weights as first MFMA operand -> acc regs hold 4 consecutive
// output columns -> 8B packed stores (32B/row per store instruction).
template <bool RELU, bool OUT_BF, bool OUT_F32, bool DEGB, int MT>
__device__ __forceinline__ void gemm_body(
    int bid,
    const unsigned short* __restrict__ A, const unsigned short* __restrict__ Bt,
    const float* __restrict__ bias, const int* __restrict__ deg, int Mvalid,
    unsigned short* __restrict__ outB, float* __restrict__ outF,
    int Nrows, int Kp, int Mp, int gN)
{
    __shared__ __align__(16) unsigned short As[128 * 64];
    __shared__ __align__(16) unsigned short Bs[128 * 64];

    // XCD-grouped decode: a row strip's MT col-blocks share (bid&7), 8 apart
    // in issue order -> A strip stays hot in L2/L3 across column passes.
    int xcd = bid & 7;
    int slot = bid >> 3;
    int c = slot % MT;
    int rsub = slot / MT;
    int rt = rsub * 8 + xcd;
    if (rt >= gN) return;
    const int rowBase = rt * 128;
    const int nBase   = c * 128;

    const int tid  = threadIdx.x;
    const int lane = tid & 63;
    const int w    = tid >> 6;
    const int wm   = w & 1, wn = w >> 1;

    f32x4 acc[4][4];
#pragma unroll
    for (int i = 0; i < 4; ++i)
#pragma unroll
        for (int j = 0; j < 4; ++j) acc[i][j] = (f32x4){0.f, 0.f, 0.f, 0.f};

    const int nkt = Kp >> 6;
    for (int kt = 0; kt < nkt; ++kt) {
        __syncthreads();
        const int k0 = kt * 64;
#pragma unroll
        for (int i = 0; i < 4; ++i) {
            int q   = i * 256 + tid;       // LDS 16B-chunk slot
            int r   = q >> 3;
            int cbg = (q & 7) ^ (r & 7);   // global chunk staged into slot q
            const unsigned short* gp = A + (size_t)(rowBase + r) * Kp + k0 + cbg * 8;
            __builtin_amdgcn_global_load_lds(
                (const __attribute__((address_space(1))) void*)gp,
                (__attribute__((address_space(3))) void*)(&As[q * 8]), 16, 0, 0);
        }
#pragma unroll
        for (int i = 0; i < 4; ++i) {
            int q   = i * 256 + tid;
            int r   = q >> 3;
            int cbg = (q & 7) ^ (r & 7);
            const unsigned short* gp = Bt + (size_t)(nBase + r) * Kp + k0 + cbg * 8;
            __builtin_amdgcn_global_load_lds(
                (const __attribute__((address_space(1))) void*)gp,
                (__attribute__((address_space(3))) void*)(&Bs[q * 8]), 16, 0, 0);
        }
        __syncthreads();
#pragma unroll
        for (int kk = 0; kk < 2; ++kk) {
            bf16x8 a[4], b[4];
            const int cb = kk * 4 + (lane >> 4);
#pragma unroll
            for (int i = 0; i < 4; ++i) {
                int r = wm * 64 + i * 16 + (lane & 15);
                a[i] = *(const bf16x8*)&As[(r * 8 + (cb ^ (r & 7))) * 8];
            }
#pragma unroll
            for (int j = 0; j < 4; ++j) {
                int r = wn * 64 + j * 16 + (lane & 15);
                b[j] = *(const bf16x8*)&Bs[(r * 8 + (cb ^ (r & 7))) * 8];
            }
#pragma unroll
            for (int i = 0; i < 4; ++i)
#pragma unroll
                for (int j = 0; j < 4; ++j)
                    // swapped: weights first -> D cols from regs, rows from lane
                    acc[i][j] = __builtin_amdgcn_mfma_f32_16x16x32_bf16(b[j], a[i], acc[i][j], 0, 0, 0);
        }
    }

    // epilogue (swapped layout): row = ...+(lane&15); col = ...+quad*4+reg
    const int quad = lane >> 4;
#pragma unroll
    for (int i = 0; i < 4; ++i) {
        int row = rowBase + wm * 64 + i * 16 + (lane & 15);
        if (row >= Nrows) continue;
        float sc = 1.f;
        if (DEGB) sc = 1.f + (float)deg[row];
#pragma unroll
        for (int j = 0; j < 4; ++j) {
            int colb = nBase + wn * 64 + j * 16 + quad * 4;
            float4 bv = (colb < Mvalid) ? *(const float4*)(bias + colb)
                                        : (float4){0.f, 0.f, 0.f, 0.f};
            float v0 = acc[i][j][0] + sc * bv.x;
            float v1 = acc[i][j][1] + sc * bv.y;
            float v2 = acc[i][j][2] + sc * bv.z;
            float v3 = acc[i][j][3] + sc * bv.w;
            if (RELU) {
                v0 = v0 > 0.f ? v0 : 0.f; v1 = v1 > 0.f ? v1 : 0.f;
                v2 = v2 > 0.f ? v2 : 0.f; v3 = v3 > 0.f ? v3 : 0.f;
            }
            if (OUT_BF) {
                ushort4 o; o.x = f2bf(v0); o.y = f2bf(v1); o.z = f2bf(v2); o.w = f2bf(v3);
                *(ushort4*)(outB + (size_t)row * Mp + colb) = o;
            }
            if (OUT_F32) {
                if (colb < Mvalid)
                    *(float4*)(outF + (size_t)row * Mvalid + colb) = (float4){v0, v1, v2, v3};
            }
        }
    }
}

template <bool RELU, bool OUT_BF, bool OUT_F32, bool DEGB, int MT>
__global__ __launch_bounds__(256, 4) void rg_gemm(
    const unsigned short* __restrict__ A, const unsigned short* __restrict__ Bt,
    const float* __restrict__ bias, const int* __restrict__ deg, int Mvalid,
    unsigned short* __restrict__ outB, float* __restrict__ outF,
    int Nrows, int Kp, int Mp, int gN)
{
    gemm_body<RELU, OUT_BF, OUT_F32, DEGB, MT>(blockIdx.x, A, Bt, bias, deg,
                                               Mvalid, outB, outF, Nrows, Kp, Mp, gN);
}

// L1 GEMM + edge scatter in one dispatch: blocks [0, gemmBlocks) do the GEMM,
// the rest scatter edges into CSR (independent work, disjoint memory; scatter
// backfills CUs as GEMM blocks retire -> hidden behind compute).
__global__ __launch_bounds__(256, 4) void rg_gemm_l1_scatter(
    const unsigned short* __restrict__ A, const unsigned short* __restrict__ Bt,
    const float* __restrict__ bias, int Mvalid,
    unsigned short* __restrict__ outB, int Nrows, int Kp, int Mp, int gN,
    int gemmBlocks, const int* __restrict__ ei, int E,
    int* __restrict__ cursor, int* __restrict__ cols)
{
    int bid = blockIdx.x;
    if (bid < gemmBlocks) {
        gemm_body<true, true, false, false, 8>(bid, A, Bt, bias, nullptr,
                                               Mvalid, outB, nullptr, Nrows, Kp, Mp, gN);
    } else {
        int e = (bid - gemmBlocks) * 256 + threadIdx.x;
        if (e < E) {
            int d = ei[E + e];
            int p = atomicAdd(&cursor[d], 1);
            cols[p] = ei[e];
        }
    }
}

// ---------------- merged scan (3 dispatches -> 1) ---------------------------
__device__ __forceinline__ void rg_gridbar(int* bar, int nb, int phase) {
    __syncthreads();
    if (threadIdx.x == 0) {
        __threadfence();
        atomicAdd(bar, 1);
        int target = phase * nb;
        while (__hip_atomic_load(bar, __ATOMIC_RELAXED, __HIP_MEMORY_SCOPE_AGENT) < target) {}
        __threadfence();
    }
    __syncthreads();
}

__global__ __launch_bounds__(1024) void rg_scan_all(
    const int* __restrict__ cnt, int* __restrict__ rowptr, int* __restrict__ cursor,
    int* __restrict__ bsums, int* bar, int Nn, int E, int nb)
{
    __shared__ int sd[1024];
    const int tid = threadIdx.x;
    const int bid = blockIdx.x;
    const int i   = bid * 1024 + tid;

    // stage 1: block-local inclusive scan of this block's 1024-chunk
    int v = (i < Nn) ? cnt[i] : 0;
    sd[tid] = v;
    __syncthreads();
    for (int off = 1; off < 1024; off <<= 1) {
        int t = (tid >= off) ? sd[tid - off] : 0;
        __syncthreads();
        sd[tid] += t;
        __syncthreads();
    }
    if (tid == 1023) bsums[bid] = sd[1023];
    rg_gridbar(bar, nb, 1);

    // stage 2: exclusive wave-scan of block sums (block 0, nb <= 64)
    if (bid == 0 && tid < 64) {
        int bv = (tid < nb) ? bsums[tid] : 0;
        int incl = bv;
#pragma unroll
        for (int off = 1; off < 64; off <<= 1) {
            int t = __shfl_up(incl, off, 64);
            if (tid >= off) incl += t;
        }
        if (tid < nb) bsums[tid] = incl - bv;   // exclusive
    }
    rg_gridbar(bar, nb, 2);

    // stage 3: write rowptr + cursor (sd persisted across barriers)
    if (i < Nn) {
        int ex = sd[tid] - v + bsums[bid];
        rowptr[i] = ex; cursor[i] = ex;
    }
    if (i == 0) rowptr[Nn] = E;
}

// ---------------- 80-dim aggregation: s[i] = pf[i] + sum_{src->i} pf[src] --
__global__ __launch_bounds__(256) void rg_agg80(
    const unsigned short* __restrict__ pf, const int* __restrict__ rowptr,
    const int* __restrict__ cols, unsigned short* __restrict__ s, int Nn)
{
    int node = blockIdx.x * 4 + (threadIdx.x >> 6);
    if (node >= Nn) return;
    int lane = threadIdx.x & 63;
    const unsigned* xp = (const unsigned*)pf;   // 64 uints per row
    size_t off = (size_t)node * 64 + lane;
    unsigned u = xp[off];
    float a0 = bf2f(u & 0xffffu), a1 = bf2f(u >> 16);
    int beg = rowptr[node], end = rowptr[node + 1];
    int e = beg;
    for (; e + 8 <= end; e += 8) {
        unsigned v[8];
#pragma unroll
        for (int t = 0; t < 8; ++t) v[t] = xp[(size_t)cols[e + t] * 64 + lane];
#pragma unroll
        for (int t = 0; t < 8; ++t) { a0 += bf2f(v[t] & 0xffffu); a1 += bf2f(v[t] >> 16); }
    }
    for (; e < end; ++e) {
        unsigned v = xp[(size_t)cols[e] * 64 + lane];
        a0 += bf2f(v & 0xffffu); a1 += bf2f(v >> 16);
    }
    unsigned o = (unsigned)f2bf(a0) | ((unsigned)f2bf(a1) << 16);
    ((unsigned*)s)[off] = o;
}

// ---------------------------------------------------------------------------
extern "C" void kernel_launch(void* const* d_in, const int* in_sizes, int n_in,
                              void* d_out, int out_size, void* d_ws, size_t ws_size,
                              hipStream_t stream)
{
    const float* feat = (const float*)d_in[0];
    const int*   ei   = (const int*)d_in[1];
    const float* W1 = (const float*)d_in[2];  const float* b1 = (const float*)d_in[3];
    const float* W2 = (const float*)d_in[4];  const float* b2 = (const float*)d_in[5];
    const float* W3 = (const float*)d_in[6];  const float* b3 = (const float*)d_in[7];
    const float* W4 = (const float*)d_in[8];  const float* b4 = (const float*)d_in[9];
    const float* Wi = (const float*)d_in[10]; const float* bi = (const float*)d_in[11];
    const float* Wg1 = (const float*)d_in[12]; const float* bg1 = (const float*)d_in[13];
    const float* Wg2 = (const float*)d_in[14]; const float* bg2 = (const float*)d_in[15];
    const float* Wo = (const float*)d_in[16]; const float* bo = (const float*)d_in[17];

    const int N = in_sizes[0] / 512;   // 50000
    const int E = in_sizes[1] / 2;     // 800000
    const int gN = (N + 127) / 128;    // 391
    const int Npad = gN * 128;         // 50048: GEMM A-loads never clamp

    char* ws = (char*)d_ws;
    size_t o = 0;
    auto alloc = [&](size_t bytes) { char* p = ws + o; o += (bytes + 255) & ~(size_t)255; return p; };
    unsigned short* bufA = (unsigned short*)alloc((size_t)Npad * 1024 * 2); // h1 / pf / g
    unsigned short* bufB = (unsigned short*)alloc((size_t)Npad * 1024 * 2); // h2 / r1
    unsigned short* bufC = (unsigned short*)alloc((size_t)Npad * 512 * 2);  // A0 / h3 / s / g2
    unsigned short* W1t = (unsigned short*)alloc((size_t)1024 * 512 * 2);
    unsigned short* W2t = (unsigned short*)alloc((size_t)1024 * 1024 * 2);
    unsigned short* W3t = (unsigned short*)alloc((size_t)512 * 1024 * 2);
    unsigned short* W4t = (unsigned short*)alloc((size_t)128 * 512 * 2);
    unsigned short* Wit = (unsigned short*)alloc((size_t)512 * 128 * 2);
    unsigned short* Wg1t = (unsigned short*)alloc((size_t)512 * 512 * 2);
    unsigned short* Wg2t = (unsigned short*)alloc((size_t)512 * 512 * 2);
    unsigned short* Wot = (unsigned short*)alloc((size_t)128 * 512 * 2);
    int* cnt    = (int*)alloc((size_t)(N + 64) * 4);  // +bar tail (one memset)
    int* bar    = cnt + N;
    int* rowptr = (int*)alloc((size_t)(N + 1) * 4);
    int* cursor = (int*)alloc((size_t)N * 4);
    int* cols   = (int*)alloc((size_t)E * 4);
    int* bsums  = (int*)alloc(256);

    float* out_mask = (float*)d_out;                  // [N,80]
    float* out_feat = (float*)d_out + (size_t)N * 80; // [N,80]

    // ---- merged preprocessing: transposes + feat convert + edge count ----
    hipMemsetAsync(cnt, 0, (size_t)(N + 64) * 4, stream);   // zeroes cnt AND bar
    {
        PreDescs d;
        const float* Ws[8]  = {W1, W2, W3, W4, Wi, Wg1, Wg2, Wo};
        unsigned short* Ts[8] = {W1t, W2t, W3t, W4t, Wit, Wg1t, Wg2t, Wot};
        int Ks[8]  = {512, 1024, 1024, 512, 80, 512, 512, 512};
        int Ms[8]  = {1024, 1024, 512, 80, 512, 512, 512, 80};
        int Kps[8] = {512, 1024, 1024, 512, 128, 512, 512, 512};
        int Mps[8] = {1024, 1024, 512, 128, 512, 512, 512, 128};
        int st = 0;
        for (int i = 0; i < 8; ++i) {
            d.W[i] = Ws[i]; d.Wt[i] = Ts[i];
            d.K[i] = Ks[i]; d.M[i] = Ms[i]; d.Kp[i] = Kps[i];
            d.ntx[i] = Mps[i] / 32;
            d.start[i] = st;
            st += (Mps[i] / 32) * (Kps[i] / 32);
        }
        d.tEnd = st;
        d.cEnd = st + (N * 512) / 1024;
        d.eEnd = d.cEnd + (E + 255) / 256;
        d.feat = feat; d.featb = bufC; d.nFeat = N * 512;
        d.ei = ei; d.E = E; d.cnt = cnt;
        rg_preprocess<<<d.eEnd, 256, 0, stream>>>(d);
    }

    // ---- CSR scan: one cooperative kernel (49 blocks) ----
    const int nb = (N + 1023) / 1024;   // 49 <= 64 (wave-scan limit)
    rg_scan_all<<<nb, 1024, 0, stream>>>(cnt, rowptr, cursor, bsums, bar, N, E, nb);

    const int rg8 = ((gN + 7) / 8) * 8;      // 392
    auto grid = [&](int MT) { return dim3(rg8 * MT); };

    // L1: h1 = relu(A0 @ W1 + b1)   [N,1024]  + edge scatter riding along
    {
        const int gemmBlocks = rg8 * 8;             // 3136
        const int scatBlocks = (E + 255) / 256;     // 3125
        rg_gemm_l1_scatter<<<dim3(gemmBlocks + scatBlocks), 256, 0, stream>>>(
            bufC, W1t, b1, 1024, bufA, N, 512, 1024, gN,
            gemmBlocks, ei, E, cursor, cols);
    }

    // L2: h2 = relu(h1 @ W2 + b2)   [N,1024]
    rg_gemm<true, true, false, false, 8><<<grid(8), 256, 0, stream>>>(bufA, W2t, b2, nullptr, 1024, bufB, nullptr, N, 1024, 1024, gN);
    // L3: h3 = relu(h2 @ W3 + b3)   [N,512]
    rg_gemm<true, true, false, false, 4><<<grid(4), 256, 0, stream>>>(bufB, W3t, b3, nullptr, 512, bufC, nullptr, N, 1024, 512, gN);
    // L4: pf = h3 @ W4 + b4  -> fp32 out_feat + bf16 padded [N,128]
    rg_gemm<false, true, true, false, 1><<<grid(1), 256, 0, stream>>>(bufC, W4t, b4, nullptr, 80, bufA, out_feat, N, 512, 128, gN);

    // 80-dim aggregation: s = pf + segsum(pf[src]) -> bufC[:, :128]
    rg_agg80<<<(N + 3) / 4, 256, 0, stream>>>(bufA, rowptr, cols, bufC, N);

    // L5: g = s @ Win + (1+deg)*bin  [N,512]   (agg moved before affine in_net)
    rg_gemm<false, true, false, true, 4><<<grid(4), 256, 0, stream>>>(bufC, Wit, bi, cnt, 512, bufA, nullptr, N, 128, 512, gN);
    // L6: r1 = relu(g @ Wg1 + bg1)  [N,512]
    rg_gemm<true, true, false, false, 4><<<grid(4), 256, 0, stream>>>(bufA, Wg1t, bg1, nullptr, 512, bufB, nullptr, N, 512, 512, gN);
    // L7: g2 = r1 @ Wg2 + bg2       [N,512]
    rg_gemm<false, true, false, false, 4><<<grid(4), 256, 0, stream>>>(bufB, Wg2t, bg2, nullptr, 512, bufC, nullptr, N, 512, 512, gN);
    // L8: mask = g2 @ Wout + bout -> fp32 out_mask
    rg_gemm<false, false, true, false, 1><<<grid(1), 256, 0, stream>>>(bufC, Wot, bo, nullptr, 80, nullptr, out_mask, N, 512, 128, gN);
}